// Round 2
// baseline (767.836 us; speedup 1.0000x reference)
//
#include <hip/hip_runtime.h>
#include <hip/hip_bf16.h>

// Problem constants (fixed by setup_inputs)
constexpr int kB   = 4;
constexpr int kT   = 2048;
constexpr int kCIN = 2048;
constexpr int kHID = 1024;
constexpr int kEMB = 256;

typedef __bf16 bf16_t;
typedef __bf16 bf16x8 __attribute__((ext_vector_type(8)));
typedef __bf16 bf16x4 __attribute__((ext_vector_type(4)));
typedef float  f32x4  __attribute__((ext_vector_type(4)));

// ---------------- cast f32 -> bf16 (4 elems/thread) ----------------
__global__ __launch_bounds__(256) void cast_bf16(const float* __restrict__ in,
                                                 bf16_t* __restrict__ out, long n4) {
  long i = (long)blockIdx.x * 256 + threadIdx.x;
  if (i >= n4) return;
  float4 v = ((const float4*)in)[i];
  bf16x4 o;
  o[0] = (bf16_t)v.x; o[1] = (bf16_t)v.y; o[2] = (bf16_t)v.z; o[3] = (bf16_t)v.w;
  ((bf16x4*)out)[i] = o;
}

// ---------------- transpose+cast w_w (CIN,HID) f32 -> (HID,CIN) bf16 ----------------
__global__ __launch_bounds__(256) void transpose_cast_ww(const float* __restrict__ in,
                                                         bf16_t* __restrict__ out) {
  __shared__ float tile[64 * 66];
  int c0 = blockIdx.y * 64;   // row in 'in' (c index)
  int h0 = blockIdx.x * 64;   // col in 'in' (h index)
#pragma unroll
  for (int k = 0; k < 16; k++) {
    int e = k * 256 + threadIdx.x;
    int r = e >> 6, c = e & 63;
    tile[r * 66 + c] = in[(size_t)(c0 + r) * kHID + h0 + c];
  }
  __syncthreads();
#pragma unroll
  for (int k = 0; k < 16; k++) {
    int e = k * 256 + threadIdx.x;
    int r = e >> 6, c = e & 63;
    out[(size_t)(h0 + r) * kCIN + c0 + c] = (bf16_t)tile[c * 66 + r];
  }
}

// ---------------- batched bf16 transpose (T x T per batch) ----------------
__global__ __launch_bounds__(256) void transpose_bf16(const bf16_t* __restrict__ in,
                                                      bf16_t* __restrict__ out) {
  __shared__ bf16_t tile[64 * 66];
  size_t base = (size_t)blockIdx.z * kT * kT;
  int r0 = blockIdx.y * 64, c0 = blockIdx.x * 64;
#pragma unroll
  for (int k = 0; k < 16; k++) {
    int e = k * 256 + threadIdx.x;
    int r = e >> 6, c = e & 63;
    tile[r * 66 + c] = in[base + (size_t)(r0 + r) * kT + c0 + c];
  }
  __syncthreads();
#pragma unroll
  for (int k = 0; k < 16; k++) {
    int e = k * 256 + threadIdx.x;
    int r = e >> 6, c = e & 63;
    out[base + (size_t)(c0 + r) * kT + r0 + c] = tile[c * 66 + r];
  }
}

// ---------------- block reductions (4 waves of 64) ----------------
__device__ __forceinline__ float blk_red_max(float v, volatile float* s) {
#pragma unroll
  for (int o = 32; o > 0; o >>= 1) v = fmaxf(v, __shfl_xor(v, o, 64));
  __syncthreads();
  if ((threadIdx.x & 63) == 0) s[threadIdx.x >> 6] = v;
  __syncthreads();
  return fmaxf(fmaxf(s[0], s[1]), fmaxf(s[2], s[3]));
}
__device__ __forceinline__ float blk_red_sum(float v, volatile float* s) {
#pragma unroll
  for (int o = 32; o > 0; o >>= 1) v += __shfl_xor(v, o, 64);
  __syncthreads();
  if ((threadIdx.x & 63) == 0) s[threadIdx.x >> 6] = v;
  __syncthreads();
  return (s[0] + s[1]) + (s[2] + s[3]);
}

// ---------------- bias_e[e] = sum_c emb_w[e,c]*w_b[c] + emb_b[e] ----------------
__global__ __launch_bounds__(256) void bias_e_kernel(const float* __restrict__ emb_w,
                                                     const float* __restrict__ w_b,
                                                     const float* __restrict__ emb_b,
                                                     float* __restrict__ out) {
  __shared__ float s[4];
  int e = blockIdx.x;
  float acc = 0.f;
  for (int c = threadIdx.x; c < kCIN; c += 256)
    acc += emb_w[(size_t)e * kCIN + c] * w_b[c];
  acc = blk_red_sum(acc, s);
  if (threadIdx.x == 0) out[e] = acc + emb_b[e];
}

// ---------------- fused moca softmax ----------------
// out[blockIdx.y] = softmax( r0*softmax(src[2y]) + r1*softmax(src[2y+1]) + rb ) per row t.
// Called twice: pass A (src=S1 scores, dst=mocab[0..1]), pass B (src=S2, dst=mocab[2..3]).
__global__ __launch_bounds__(256) void moca_kernel(const float* __restrict__ src,
                                                   bf16_t* __restrict__ dst,
                                                   const float* __restrict__ rou_w,
                                                   const float* __restrict__ rou_b) {
  __shared__ float s[4];
  const int t = blockIdx.x, b = blockIdx.y;
  const size_t T2 = (size_t)kT * kT;
  const float* rA = src + (size_t)(2 * b) * T2 + (size_t)t * kT;
  const float* rB = rA + T2;
  const int base = threadIdx.x * 8;

  float va[8], vb[8];
  {
    float4 a0 = *(const float4*)(rA + base), a1 = *(const float4*)(rA + base + 4);
    float4 b0 = *(const float4*)(rB + base), b1 = *(const float4*)(rB + base + 4);
    va[0]=a0.x; va[1]=a0.y; va[2]=a0.z; va[3]=a0.w; va[4]=a1.x; va[5]=a1.y; va[6]=a1.z; va[7]=a1.w;
    vb[0]=b0.x; vb[1]=b0.y; vb[2]=b0.z; vb[3]=b0.w; vb[4]=b1.x; vb[5]=b1.y; vb[6]=b1.z; vb[7]=b1.w;
  }
  float m = -1e30f;
#pragma unroll
  for (int j = 0; j < 8; j++) m = fmaxf(m, va[j]);
  m = blk_red_max(m, s);
  float acc = 0.f;
#pragma unroll
  for (int j = 0; j < 8; j++) { va[j] = __expf(va[j] - m); acc += va[j]; }
  float invA = 1.f / blk_red_sum(acc, s);

  m = -1e30f;
#pragma unroll
  for (int j = 0; j < 8; j++) m = fmaxf(m, vb[j]);
  m = blk_red_max(m, s);
  acc = 0.f;
#pragma unroll
  for (int j = 0; j < 8; j++) { vb[j] = __expf(vb[j] - m); acc += vb[j]; }
  float invB = 1.f / blk_red_sum(acc, s);

  const float r0 = rou_w[0], r1 = rou_w[1], rb = rou_b[0];
#pragma unroll
  for (int j = 0; j < 8; j++) va[j] = r0 * va[j] * invA + r1 * vb[j] * invB + rb;

  m = -1e30f;
#pragma unroll
  for (int j = 0; j < 8; j++) m = fmaxf(m, va[j]);
  m = blk_red_max(m, s);
  acc = 0.f;
#pragma unroll
  for (int j = 0; j < 8; j++) { va[j] = __expf(va[j] - m); acc += va[j]; }
  float invC = 1.f / blk_red_sum(acc, s);

  bf16x8 o;
#pragma unroll
  for (int j = 0; j < 8; j++) o[j] = (bf16_t)(va[j] * invC);
  *(bf16x8*)(dst + (size_t)b * T2 + (size_t)t * kT + base) = o;
}

// ---------------- NT GEMM: C[m,n] = sum_k A[m,k]*B[n,k]  (bf16 in, fp32 acc) ----------------
// Tile 128x128xBK32, 256 threads (2x2 waves of 64x64), mfma_f32_16x16x32_bf16.
// lda=ldb=K, ldc=N. Optional biasN[n], biasM[m], fp32 addend add32 (same layout as C).
template <bool OUT_BF16>
__global__ __launch_bounds__(256) void gemm_nt(const bf16_t* __restrict__ A,
                                               const bf16_t* __restrict__ B,
                                               void* __restrict__ Cv,
                                               int M, int N, int K,
                                               long strideA, long strideB, long strideC,
                                               const float* __restrict__ biasN,
                                               const float* __restrict__ biasM,
                                               const float* __restrict__ add32) {
  __shared__ bf16_t sA[128 * 40];  // pad 32->40: conflict-free ds_read_b128
  __shared__ bf16_t sB[128 * 40];

  const int tid = threadIdx.x;
  const int lane = tid & 63, wave = tid >> 6;
  const int wm = wave & 1, wn = wave >> 1;
  const int lm = lane & 15, q = lane >> 4;

  A += (size_t)blockIdx.z * strideA;
  B += (size_t)blockIdx.z * strideB;
  const int m0 = blockIdx.x * 128, n0 = blockIdx.y * 128;

  f32x4 acc[4][4];
#pragma unroll
  for (int i = 0; i < 4; i++)
#pragma unroll
    for (int j = 0; j < 4; j++)
#pragma unroll
      for (int r = 0; r < 4; r++) acc[i][j][r] = 0.f;

  // staging assignment: thread -> (row = tid>>2 and +64, col chunk = (tid&3)*8)
  const int vrow = tid >> 2;
  const int vcol = (tid & 3) * 8;
  const bf16_t* gA = A + (size_t)(m0 + vrow) * K + vcol;
  const bf16_t* gB = B + (size_t)(n0 + vrow) * K + vcol;

  for (int k0 = 0; k0 < K; k0 += 32) {
    __syncthreads();
    bf16x8 a0 = *(const bf16x8*)(gA + k0);
    bf16x8 a1 = *(const bf16x8*)(gA + (size_t)64 * K + k0);
    bf16x8 b0 = *(const bf16x8*)(gB + k0);
    bf16x8 b1 = *(const bf16x8*)(gB + (size_t)64 * K + k0);
    *(bf16x8*)(&sA[vrow * 40 + vcol]) = a0;
    *(bf16x8*)(&sA[(vrow + 64) * 40 + vcol]) = a1;
    *(bf16x8*)(&sB[vrow * 40 + vcol]) = b0;
    *(bf16x8*)(&sB[(vrow + 64) * 40 + vcol]) = b1;
    __syncthreads();

    bf16x8 af[4], bfr[4];
#pragma unroll
    for (int i = 0; i < 4; i++)
      af[i] = *(const bf16x8*)(&sA[(wm * 64 + i * 16 + lm) * 40 + q * 8]);
#pragma unroll
    for (int j = 0; j < 4; j++)
      bfr[j] = *(const bf16x8*)(&sB[(wn * 64 + j * 16 + lm) * 40 + q * 8]);
#pragma unroll
    for (int i = 0; i < 4; i++)
#pragma unroll
      for (int j = 0; j < 4; j++)
        acc[i][j] = __builtin_amdgcn_mfma_f32_16x16x32_bf16(af[i], bfr[j], acc[i][j], 0, 0, 0);
  }

  // epilogue: C/D layout col=lane&15, row=(lane>>4)*4+reg  [m89/m91 verified]
  const size_t cb = (size_t)blockIdx.z * strideC;
#pragma unroll
  for (int i = 0; i < 4; i++) {
    const int gmb = m0 + wm * 64 + i * 16 + q * 4;
#pragma unroll
    for (int j = 0; j < 4; j++) {
      const int gn = n0 + wn * 64 + j * 16 + lm;
      float bn = biasN ? biasN[gn] : 0.f;
#pragma unroll
      for (int r = 0; r < 4; r++) {
        const int gm = gmb + r;
        float v = acc[i][j][r] + bn;
        if (biasM) v += biasM[gm];
        const size_t idx = cb + (size_t)gm * N + gn;
        if (add32) v += add32[idx];
        if (OUT_BF16) ((bf16_t*)Cv)[idx] = (bf16_t)v;
        else          ((float*)Cv)[idx] = v;
      }
    }
  }
}

extern "C" void kernel_launch(void* const* d_in, const int* in_sizes, int n_in,
                              void* d_out, int out_size, void* d_ws, size_t ws_size,
                              hipStream_t stream) {
  const float* x       = (const float*)d_in[0];
  const float* theta_w = (const float*)d_in[1];
  const float* theta_b = (const float*)d_in[2];
  const float* phi_w   = (const float*)d_in[3];
  const float* phi_b   = (const float*)d_in[4];
  const float* g_w     = (const float*)d_in[5];
  const float* g_b     = (const float*)d_in[6];
  const float* rou_w   = (const float*)d_in[7];
  const float* rou_b   = (const float*)d_in[8];
  const float* w_w     = (const float*)d_in[9];
  const float* w_b     = (const float*)d_in[10];
  const float* emb_w   = (const float*)d_in[11];
  const float* emb_b   = (const float*)d_in[12];
  float* out = (float*)d_out;

  char* ws = (char*)d_ws;
  size_t off = 0;
  auto alloc = [&](size_t bytes) -> char* {
    off = (off + 255) & ~(size_t)255;
    char* p = ws + off;
    off += bytes;
    return p;
  };

  const size_t BT = (size_t)kB * kT;         // 8192
  const size_t T2 = (size_t)kT * kT;         // 4M

  // Static layout, total ~193.5 MiB (must stay < 256 MiB — round-1 lesson)
  bf16_t* xbf   = (bf16_t*)alloc(BT * kCIN * 2);             // 33.5 MB
  bf16_t* thbf  = (bf16_t*)alloc((size_t)kHID * kCIN * 2);   // 4.2 MB
  bf16_t* phbf  = (bf16_t*)alloc((size_t)kHID * kCIN * 2);   // 4.2 MB
  bf16_t* gbf   = (bf16_t*)alloc((size_t)kHID * kCIN * 2);   // 4.2 MB
  bf16_t* embbf = (bf16_t*)alloc((size_t)kEMB * kCIN * 2);   // 1.0 MB
  bf16_t* wwT   = (bf16_t*)alloc((size_t)kHID * kCIN * 2);   // 4.2 MB
  bf16_t* xt    = (bf16_t*)alloc(BT * kHID * 2);             // 16.8 MB
  bf16_t* xphi  = (bf16_t*)alloc(BT * kHID * 2);             // 16.8 MB (contiguous after xt)
  bf16_t* xgT   = (bf16_t*)alloc((size_t)kB * kHID * kT * 2);// 16.8 MB
  bf16_t* mocab = (bf16_t*)alloc((size_t)kB * T2 * 2);       // 33.5 MB
  bf16_t* Mbf   = (bf16_t*)alloc((size_t)kEMB * kHID * 2);   // 0.5 MB
  float*  biase = (float*)alloc((size_t)kEMB * 4);
  float*  S     = (float*)alloc((size_t)kB * T2 * 4);        // 67.1 MB (S1 then S2)
  // aliases over dead regions (stream order makes these safe):
  bf16_t* mocaT = (bf16_t*)xt;                       // xt+xphi dead after S2 GEMM (33.5 MB)
  bf16_t* yT    = (bf16_t*)S;                        // S dead after moca pass B (needs 16.8 MB)
  float*  xe    = (float*)((char*)S + 33554432);     // disjoint from yT (needs 8.4 MB)

  // casts + weight prep
  long n4;
  n4 = (long)(BT * kCIN / 4);
  cast_bf16<<<dim3((n4 + 255) / 256), 256, 0, stream>>>(x, xbf, n4);
  n4 = (long)((size_t)kHID * kCIN / 4);
  cast_bf16<<<dim3((n4 + 255) / 256), 256, 0, stream>>>(theta_w, thbf, n4);
  cast_bf16<<<dim3((n4 + 255) / 256), 256, 0, stream>>>(phi_w, phbf, n4);
  cast_bf16<<<dim3((n4 + 255) / 256), 256, 0, stream>>>(g_w, gbf, n4);
  n4 = (long)((size_t)kEMB * kCIN / 4);
  cast_bf16<<<dim3((n4 + 255) / 256), 256, 0, stream>>>(emb_w, embbf, n4);
  transpose_cast_ww<<<dim3(kHID / 64, kCIN / 64), 256, 0, stream>>>(w_w, wwT);
  bias_e_kernel<<<dim3(kEMB), 256, 0, stream>>>(emb_w, w_b, emb_b, biase);

  // xt = x @ theta^T + theta_b   (8192 x 1024, K=2048) -> bf16
  gemm_nt<true><<<dim3(64, 8, 1), 256, 0, stream>>>(xbf, thbf, xt, 8192, 1024, 2048,
                                                    0, 0, 0, theta_b, nullptr, nullptr);
  // xphi = x @ phi^T + phi_b
  gemm_nt<true><<<dim3(64, 8, 1), 256, 0, stream>>>(xbf, phbf, xphi, 8192, 1024, 2048,
                                                    0, 0, 0, phi_b, nullptr, nullptr);
  // xgT[b] = g_w @ x[b]^T + g_b[m]   (1024 x 2048 per batch) -> bf16
  gemm_nt<true><<<dim3(8, 16, kB), 256, 0, stream>>>(gbf, xbf, xgT, 1024, 2048, 2048,
                                                     0, (long)(kT * (size_t)kCIN),
                                                     (long)((size_t)kHID * kT),
                                                     nullptr, g_b, nullptr);
  // M = emb @ w_w  (256 x 1024, K=2048) -> bf16
  gemm_nt<true><<<dim3(2, 8, 1), 256, 0, stream>>>(embbf, wwT, Mbf, 256, 1024, 2048,
                                                   0, 0, 0, nullptr, nullptr, nullptr);

  // S <- S1[b] = x[b] @ x[b]^T   fp32
  gemm_nt<false><<<dim3(16, 16, kB), 256, 0, stream>>>(xbf, xbf, S, 2048, 2048, 2048,
                                                       (long)(kT * (size_t)kCIN),
                                                       (long)(kT * (size_t)kCIN),
                                                       (long)T2, nullptr, nullptr, nullptr);
  // moca pass A: batches 0,1 read S1 pairs (0,1),(2,3)
  moca_kernel<<<dim3(kT, 2), 256, 0, stream>>>(S, mocab, rou_w, rou_b);

  // S <- S2[b] = xphi[b] @ xt[b]^T  fp32  (K=1024)
  gemm_nt<false><<<dim3(16, 16, kB), 256, 0, stream>>>(xphi, xt, S, 2048, 2048, 1024,
                                                       (long)(kT * (size_t)kHID),
                                                       (long)(kT * (size_t)kHID),
                                                       (long)T2, nullptr, nullptr, nullptr);
  // moca pass B: batches 2,3 read S2 pairs (0,1),(2,3)
  moca_kernel<<<dim3(kT, 2), 256, 0, stream>>>(S, mocab + 2 * T2, rou_w, rou_b);

  // mocaT (reads mocab, writes over dead xt/xphi region)
  transpose_bf16<<<dim3(kT / 64, kT / 64, kB), 256, 0, stream>>>(mocab, mocaT);
  // yT[b] = mocaT[b] @ xgT[b]^T   (2048 x 1024, K=2048) -> bf16 (over dead S region)
  gemm_nt<true><<<dim3(16, 8, kB), 256, 0, stream>>>(mocaT, xgT, yT, 2048, 1024, 2048,
                                                     (long)T2, (long)((size_t)kHID * kT),
                                                     (long)(kT * (size_t)kHID),
                                                     nullptr, nullptr, nullptr);
  // xe = x @ emb^T  (8192 x 256, K=2048) fp32 (disjoint part of dead S region)
  gemm_nt<false><<<dim3(64, 2, 1), 256, 0, stream>>>(xbf, embbf, xe, 8192, 256, 2048,
                                                     0, 0, 0, nullptr, nullptr, nullptr);
  // out = yT @ M^T + xe + bias_e  (8192 x 256, K=1024) fp32 -> d_out
  gemm_nt<false><<<dim3(64, 2, 1), 256, 0, stream>>>(yT, Mbf, out, 8192, 256, 1024,
                                                     0, 0, 0, biase, nullptr, xe);
}

// Round 3
// 747.214 us; speedup vs baseline: 1.0276x; 1.0276x over previous
//
#include <hip/hip_runtime.h>
#include <hip/hip_bf16.h>

// Problem constants (fixed by setup_inputs)
constexpr int kB   = 4;
constexpr int kT   = 2048;
constexpr int kCIN = 2048;
constexpr int kHID = 1024;
constexpr int kEMB = 256;

typedef __bf16 bf16_t;
typedef __bf16 bf16x8 __attribute__((ext_vector_type(8)));
typedef __bf16 bf16x4 __attribute__((ext_vector_type(4)));
typedef float  f32x4  __attribute__((ext_vector_type(4)));

// async global->LDS 16B/lane (CK amd_direct_load pattern; LDS dest = uniform base + lane*16)
__device__ __forceinline__ void gll16(const void* g, void* l) {
  auto lp = reinterpret_cast<__attribute__((address_space(3))) uint32_t*>(
      reinterpret_cast<uintptr_t>(l));
  __builtin_amdgcn_global_load_lds(static_cast<const uint32_t*>(g), lp, 16, 0, 0);
}

// ---------------- cast f32 -> bf16 (4 elems/thread) ----------------
__global__ __launch_bounds__(256) void cast_bf16(const float* __restrict__ in,
                                                 bf16_t* __restrict__ out, long n4) {
  long i = (long)blockIdx.x * 256 + threadIdx.x;
  if (i >= n4) return;
  float4 v = ((const float4*)in)[i];
  bf16x4 o;
  o[0] = (bf16_t)v.x; o[1] = (bf16_t)v.y; o[2] = (bf16_t)v.z; o[3] = (bf16_t)v.w;
  ((bf16x4*)out)[i] = o;
}

// ---------------- transpose+cast w_w (CIN,HID) f32 -> (HID,CIN) bf16 ----------------
__global__ __launch_bounds__(256) void transpose_cast_ww(const float* __restrict__ in,
                                                         bf16_t* __restrict__ out) {
  __shared__ float tile[64 * 66];
  int c0 = blockIdx.y * 64;   // row in 'in' (c index)
  int h0 = blockIdx.x * 64;   // col in 'in' (h index)
#pragma unroll
  for (int k = 0; k < 16; k++) {
    int e = k * 256 + threadIdx.x;
    int r = e >> 6, c = e & 63;
    tile[r * 66 + c] = in[(size_t)(c0 + r) * kHID + h0 + c];
  }
  __syncthreads();
#pragma unroll
  for (int k = 0; k < 16; k++) {
    int e = k * 256 + threadIdx.x;
    int r = e >> 6, c = e & 63;
    out[(size_t)(h0 + r) * kCIN + c0 + c] = (bf16_t)tile[c * 66 + r];
  }
}

// ---------------- batched bf16 transpose (T x T per batch) ----------------
__global__ __launch_bounds__(256) void transpose_bf16(const bf16_t* __restrict__ in,
                                                      bf16_t* __restrict__ out) {
  __shared__ bf16_t tile[64 * 66];
  size_t base = (size_t)blockIdx.z * kT * kT;
  int r0 = blockIdx.y * 64, c0 = blockIdx.x * 64;
#pragma unroll
  for (int k = 0; k < 16; k++) {
    int e = k * 256 + threadIdx.x;
    int r = e >> 6, c = e & 63;
    tile[r * 66 + c] = in[base + (size_t)(r0 + r) * kT + c0 + c];
  }
  __syncthreads();
#pragma unroll
  for (int k = 0; k < 16; k++) {
    int e = k * 256 + threadIdx.x;
    int r = e >> 6, c = e & 63;
    out[base + (size_t)(c0 + r) * kT + r0 + c] = tile[c * 66 + r];
  }
}

// ---------------- block reductions (4 waves of 64) ----------------
__device__ __forceinline__ float blk_red_max(float v, volatile float* s) {
#pragma unroll
  for (int o = 32; o > 0; o >>= 1) v = fmaxf(v, __shfl_xor(v, o, 64));
  __syncthreads();
  if ((threadIdx.x & 63) == 0) s[threadIdx.x >> 6] = v;
  __syncthreads();
  return fmaxf(fmaxf(s[0], s[1]), fmaxf(s[2], s[3]));
}
__device__ __forceinline__ float blk_red_sum(float v, volatile float* s) {
#pragma unroll
  for (int o = 32; o > 0; o >>= 1) v += __shfl_xor(v, o, 64);
  __syncthreads();
  if ((threadIdx.x & 63) == 0) s[threadIdx.x >> 6] = v;
  __syncthreads();
  return (s[0] + s[1]) + (s[2] + s[3]);
}

// ---------------- bias_e[e] = sum_c emb_w[e,c]*w_b[c] + emb_b[e] ----------------
__global__ __launch_bounds__(256) void bias_e_kernel(const float* __restrict__ emb_w,
                                                     const float* __restrict__ w_b,
                                                     const float* __restrict__ emb_b,
                                                     float* __restrict__ out) {
  __shared__ float s[4];
  int e = blockIdx.x;
  float acc = 0.f;
  for (int c = threadIdx.x; c < kCIN; c += 256)
    acc += emb_w[(size_t)e * kCIN + c] * w_b[c];
  acc = blk_red_sum(acc, s);
  if (threadIdx.x == 0) out[e] = acc + emb_b[e];
}

// ---------------- fused moca softmax ----------------
// out[blockIdx.y] = softmax( r0*softmax(src[2y]) + r1*softmax(src[2y+1]) + rb ) per row t.
// Called twice: pass A (src=S1 scores, dst=mocab[0..1]), pass B (src=S2, dst=mocab[2..3]).
__global__ __launch_bounds__(256) void moca_kernel(const float* __restrict__ src,
                                                   bf16_t* __restrict__ dst,
                                                   const float* __restrict__ rou_w,
                                                   const float* __restrict__ rou_b) {
  __shared__ float s[4];
  const int t = blockIdx.x, b = blockIdx.y;
  const size_t T2 = (size_t)kT * kT;
  const float* rA = src + (size_t)(2 * b) * T2 + (size_t)t * kT;
  const float* rB = rA + T2;
  const int base = threadIdx.x * 8;

  float va[8], vb[8];
  {
    float4 a0 = *(const float4*)(rA + base), a1 = *(const float4*)(rA + base + 4);
    float4 b0 = *(const float4*)(rB + base), b1 = *(const float4*)(rB + base + 4);
    va[0]=a0.x; va[1]=a0.y; va[2]=a0.z; va[3]=a0.w; va[4]=a1.x; va[5]=a1.y; va[6]=a1.z; va[7]=a1.w;
    vb[0]=b0.x; vb[1]=b0.y; vb[2]=b0.z; vb[3]=b0.w; vb[4]=b1.x; vb[5]=b1.y; vb[6]=b1.z; vb[7]=b1.w;
  }
  float m = -1e30f;
#pragma unroll
  for (int j = 0; j < 8; j++) m = fmaxf(m, va[j]);
  m = blk_red_max(m, s);
  float acc = 0.f;
#pragma unroll
  for (int j = 0; j < 8; j++) { va[j] = __expf(va[j] - m); acc += va[j]; }
  float invA = 1.f / blk_red_sum(acc, s);

  m = -1e30f;
#pragma unroll
  for (int j = 0; j < 8; j++) m = fmaxf(m, vb[j]);
  m = blk_red_max(m, s);
  acc = 0.f;
#pragma unroll
  for (int j = 0; j < 8; j++) { vb[j] = __expf(vb[j] - m); acc += vb[j]; }
  float invB = 1.f / blk_red_sum(acc, s);

  const float r0 = rou_w[0], r1 = rou_w[1], rb = rou_b[0];
#pragma unroll
  for (int j = 0; j < 8; j++) va[j] = r0 * va[j] * invA + r1 * vb[j] * invB + rb;

  m = -1e30f;
#pragma unroll
  for (int j = 0; j < 8; j++) m = fmaxf(m, va[j]);
  m = blk_red_max(m, s);
  acc = 0.f;
#pragma unroll
  for (int j = 0; j < 8; j++) { va[j] = __expf(va[j] - m); acc += va[j]; }
  float invC = 1.f / blk_red_sum(acc, s);

  bf16x8 o;
#pragma unroll
  for (int j = 0; j < 8; j++) o[j] = (bf16_t)(va[j] * invC);
  *(bf16x8*)(dst + (size_t)b * T2 + (size_t)t * kT + base) = o;
}

// ---------------- NT GEMM: C[m,n] = sum_k A[m,k]*B[n,k]  (bf16 in, fp32 acc) ----------------
// Tile 128x128xBK32, 256 threads (2x2 waves of 64x64), mfma_f32_16x16x32_bf16.
// m97-style staging: global_load_lds width=16, unpadded [128][32] LDS tiles.
// lda=ldb=K, ldc=N. Optional biasN[n], biasM[m], fp32 addend add32 (same layout as C).
template <bool OUT_BF16>
__global__ __launch_bounds__(256) void gemm_nt(const bf16_t* __restrict__ A,
                                               const bf16_t* __restrict__ B,
                                               void* __restrict__ Cv,
                                               int M, int N, int K,
                                               long strideA, long strideB, long strideC,
                                               const float* __restrict__ biasN,
                                               const float* __restrict__ biasM,
                                               const float* __restrict__ add32) {
  __shared__ bf16_t sA[128 * 32];  // unpadded: global_load_lds deposits lane-contiguous
  __shared__ bf16_t sB[128 * 32];

  const int tid = threadIdx.x;
  const int lane = tid & 63, wave = tid >> 6;
  const int wm = wave & 1, wn = wave >> 1;
  const int lm = lane & 15, q = lane >> 4;

  A += (size_t)blockIdx.z * strideA;
  B += (size_t)blockIdx.z * strideB;
  const int m0 = blockIdx.x * 128, n0 = blockIdx.y * 128;

  f32x4 acc[4][4];
#pragma unroll
  for (int i = 0; i < 4; i++)
#pragma unroll
    for (int j = 0; j < 4; j++)
#pragma unroll
      for (int r = 0; r < 4; r++) acc[i][j][r] = 0.f;

  // staging: wave w deposits rows [w*16, w*16+16) and [64+w*16, ...) of each tile.
  // lane i -> row w*16 + (i>>2), 16B chunk (i&3). LDS slot = base + i*16B (HW).
  const int srow = wave * 16 + (lane >> 2);
  const int scol = (lane & 3) * 8;
  const bf16_t* gA0 = A + (size_t)(m0 + srow) * K + scol;
  const bf16_t* gA1 = gA0 + (size_t)64 * K;
  const bf16_t* gB0 = B + (size_t)(n0 + srow) * K + scol;
  const bf16_t* gB1 = gB0 + (size_t)64 * K;
  bf16_t* lA0 = &sA[wave * 16 * 32];
  bf16_t* lA1 = &sA[(64 + wave * 16) * 32];
  bf16_t* lB0 = &sB[wave * 16 * 32];
  bf16_t* lB1 = &sB[(64 + wave * 16) * 32];

  for (int k0 = 0; k0 < K; k0 += 32) {
    __syncthreads();
    gll16(gA0 + k0, lA0);
    gll16(gA1 + k0, lA1);
    gll16(gB0 + k0, lB0);
    gll16(gB1 + k0, lB1);
    __syncthreads();  // compiler emits s_waitcnt vmcnt(0) before s_barrier -> staging complete

    bf16x8 af[4], bfr[4];
#pragma unroll
    for (int i = 0; i < 4; i++)
      af[i] = *(const bf16x8*)(&sA[(wm * 64 + i * 16 + lm) * 32 + q * 8]);
#pragma unroll
    for (int j = 0; j < 4; j++)
      bfr[j] = *(const bf16x8*)(&sB[(wn * 64 + j * 16 + lm) * 32 + q * 8]);
#pragma unroll
    for (int i = 0; i < 4; i++)
#pragma unroll
      for (int j = 0; j < 4; j++)
        acc[i][j] = __builtin_amdgcn_mfma_f32_16x16x32_bf16(af[i], bfr[j], acc[i][j], 0, 0, 0);
  }

  // epilogue: C/D layout col=lane&15, row=(lane>>4)*4+reg  [m89/m91 verified]
  const size_t cb = (size_t)blockIdx.z * strideC;
#pragma unroll
  for (int i = 0; i < 4; i++) {
    const int gmb = m0 + wm * 64 + i * 16 + q * 4;
#pragma unroll
    for (int j = 0; j < 4; j++) {
      const int gn = n0 + wn * 64 + j * 16 + lm;
      float bn = biasN ? biasN[gn] : 0.f;
#pragma unroll
      for (int r = 0; r < 4; r++) {
        const int gm = gmb + r;
        float v = acc[i][j][r] + bn;
        if (biasM) v += biasM[gm];
        const size_t idx = cb + (size_t)gm * N + gn;
        if (add32) v += add32[idx];
        if (OUT_BF16) ((bf16_t*)Cv)[idx] = (bf16_t)v;
        else          ((float*)Cv)[idx] = v;
      }
    }
  }
}

extern "C" void kernel_launch(void* const* d_in, const int* in_sizes, int n_in,
                              void* d_out, int out_size, void* d_ws, size_t ws_size,
                              hipStream_t stream) {
  const float* x       = (const float*)d_in[0];
  const float* theta_w = (const float*)d_in[1];
  const float* theta_b = (const float*)d_in[2];
  const float* phi_w   = (const float*)d_in[3];
  const float* phi_b   = (const float*)d_in[4];
  const float* g_w     = (const float*)d_in[5];
  const float* g_b     = (const float*)d_in[6];
  const float* rou_w   = (const float*)d_in[7];
  const float* rou_b   = (const float*)d_in[8];
  const float* w_w     = (const float*)d_in[9];
  const float* w_b     = (const float*)d_in[10];
  const float* emb_w   = (const float*)d_in[11];
  const float* emb_b   = (const float*)d_in[12];
  float* out = (float*)d_out;

  char* ws = (char*)d_ws;
  size_t off = 0;
  auto alloc = [&](size_t bytes) -> char* {
    off = (off + 255) & ~(size_t)255;
    char* p = ws + off;
    off += bytes;
    return p;
  };

  const size_t BT = (size_t)kB * kT;         // 8192
  const size_t T2 = (size_t)kT * kT;         // 4M

  // Static layout, total ~193.5 MiB (must stay < 256 MiB — round-1 lesson)
  bf16_t* xbf   = (bf16_t*)alloc(BT * kCIN * 2);             // 33.5 MB
  bf16_t* thbf  = (bf16_t*)alloc((size_t)kHID * kCIN * 2);   // 4.2 MB
  bf16_t* phbf  = (bf16_t*)alloc((size_t)kHID * kCIN * 2);   // 4.2 MB
  bf16_t* gbf   = (bf16_t*)alloc((size_t)kHID * kCIN * 2);   // 4.2 MB
  bf16_t* embbf = (bf16_t*)alloc((size_t)kEMB * kCIN * 2);   // 1.0 MB
  bf16_t* wwT   = (bf16_t*)alloc((size_t)kHID * kCIN * 2);   // 4.2 MB
  bf16_t* xt    = (bf16_t*)alloc(BT * kHID * 2);             // 16.8 MB
  bf16_t* xphi  = (bf16_t*)alloc(BT * kHID * 2);             // 16.8 MB (contiguous after xt)
  bf16_t* xgT   = (bf16_t*)alloc((size_t)kB * kHID * kT * 2);// 16.8 MB
  bf16_t* mocab = (bf16_t*)alloc((size_t)kB * T2 * 2);       // 33.5 MB
  bf16_t* Mbf   = (bf16_t*)alloc((size_t)kEMB * kHID * 2);   // 0.5 MB
  float*  biase = (float*)alloc((size_t)kEMB * 4);
  float*  S     = (float*)alloc((size_t)kB * T2 * 4);        // 67.1 MB (S1 then S2)
  // aliases over dead regions (stream order makes these safe):
  bf16_t* mocaT = (bf16_t*)xt;                       // xt+xphi dead after S2 GEMM (33.5 MB)
  bf16_t* yT    = (bf16_t*)S;                        // S dead after moca pass B (needs 16.8 MB)
  float*  xe    = (float*)((char*)S + 33554432);     // disjoint from yT (needs 8.4 MB)

  // casts + weight prep
  long n4;
  n4 = (long)(BT * kCIN / 4);
  cast_bf16<<<dim3((n4 + 255) / 256), 256, 0, stream>>>(x, xbf, n4);
  n4 = (long)((size_t)kHID * kCIN / 4);
  cast_bf16<<<dim3((n4 + 255) / 256), 256, 0, stream>>>(theta_w, thbf, n4);
  cast_bf16<<<dim3((n4 + 255) / 256), 256, 0, stream>>>(phi_w, phbf, n4);
  cast_bf16<<<dim3((n4 + 255) / 256), 256, 0, stream>>>(g_w, gbf, n4);
  n4 = (long)((size_t)kEMB * kCIN / 4);
  cast_bf16<<<dim3((n4 + 255) / 256), 256, 0, stream>>>(emb_w, embbf, n4);
  transpose_cast_ww<<<dim3(kHID / 64, kCIN / 64), 256, 0, stream>>>(w_w, wwT);
  bias_e_kernel<<<dim3(kEMB), 256, 0, stream>>>(emb_w, w_b, emb_b, biase);

  // xt = x @ theta^T + theta_b   (8192 x 1024, K=2048) -> bf16
  gemm_nt<true><<<dim3(64, 8, 1), 256, 0, stream>>>(xbf, thbf, xt, 8192, 1024, 2048,
                                                    0, 0, 0, theta_b, nullptr, nullptr);
  // xphi = x @ phi^T + phi_b
  gemm_nt<true><<<dim3(64, 8, 1), 256, 0, stream>>>(xbf, phbf, xphi, 8192, 1024, 2048,
                                                    0, 0, 0, phi_b, nullptr, nullptr);
  // xgT[b] = g_w @ x[b]^T + g_b[m]   (1024 x 2048 per batch) -> bf16
  gemm_nt<true><<<dim3(8, 16, kB), 256, 0, stream>>>(gbf, xbf, xgT, 1024, 2048, 2048,
                                                     0, (long)(kT * (size_t)kCIN),
                                                     (long)((size_t)kHID * kT),
                                                     nullptr, g_b, nullptr);
  // M = emb @ w_w  (256 x 1024, K=2048) -> bf16
  gemm_nt<true><<<dim3(2, 8, 1), 256, 0, stream>>>(embbf, wwT, Mbf, 256, 1024, 2048,
                                                   0, 0, 0, nullptr, nullptr, nullptr);

  // S <- S1[b] = x[b] @ x[b]^T   fp32
  gemm_nt<false><<<dim3(16, 16, kB), 256, 0, stream>>>(xbf, xbf, S, 2048, 2048, 2048,
                                                       (long)(kT * (size_t)kCIN),
                                                       (long)(kT * (size_t)kCIN),
                                                       (long)T2, nullptr, nullptr, nullptr);
  // moca pass A: batches 0,1 read S1 pairs (0,1),(2,3)
  moca_kernel<<<dim3(kT, 2), 256, 0, stream>>>(S, mocab, rou_w, rou_b);

  // S <- S2[b] = xphi[b] @ xt[b]^T  fp32  (K=1024)
  gemm_nt<false><<<dim3(16, 16, kB), 256, 0, stream>>>(xphi, xt, S, 2048, 2048, 1024,
                                                       (long)(kT * (size_t)kHID),
                                                       (long)(kT * (size_t)kHID),
                                                       (long)T2, nullptr, nullptr, nullptr);
  // moca pass B: batches 2,3 read S2 pairs (0,1),(2,3)
  moca_kernel<<<dim3(kT, 2), 256, 0, stream>>>(S, mocab + 2 * T2, rou_w, rou_b);

  // mocaT (reads mocab, writes over dead xt/xphi region)
  transpose_bf16<<<dim3(kT / 64, kT / 64, kB), 256, 0, stream>>>(mocab, mocaT);
  // yT[b] = mocaT[b] @ xgT[b]^T   (2048 x 1024, K=2048) -> bf16 (over dead S region)
  gemm_nt<true><<<dim3(16, 8, kB), 256, 0, stream>>>(mocaT, xgT, yT, 2048, 1024, 2048,
                                                     (long)T2, (long)((size_t)kHID * kT),
                                                     (long)(kT * (size_t)kHID),
                                                     nullptr, nullptr, nullptr);
  // xe = x @ emb^T  (8192 x 256, K=2048) fp32 (disjoint part of dead S region)
  gemm_nt<false><<<dim3(64, 2, 1), 256, 0, stream>>>(xbf, embbf, xe, 8192, 256, 2048,
                                                     0, 0, 0, nullptr, nullptr, nullptr);
  // out = yT @ M^T + xe + bias_e  (8192 x 256, K=1024) fp32 -> d_out
  gemm_nt<false><<<dim3(64, 2, 1), 256, 0, stream>>>(yT, Mbf, out, 8192, 256, 1024,
                                                     0, 0, 0, biase, nullptr, xe);
}

// Round 4
// 633.027 us; speedup vs baseline: 1.2130x; 1.1804x over previous
//
#include <hip/hip_runtime.h>
#include <hip/hip_bf16.h>

// Problem constants (fixed by setup_inputs)
constexpr int kB   = 4;
constexpr int kT   = 2048;
constexpr int kCIN = 2048;
constexpr int kHID = 1024;
constexpr int kEMB = 256;

typedef __bf16 bf16_t;
typedef __bf16 bf16x8 __attribute__((ext_vector_type(8)));
typedef __bf16 bf16x4 __attribute__((ext_vector_type(4)));
typedef float  f32x4  __attribute__((ext_vector_type(4)));

// async global->LDS 16B/lane (LDS dest = wave-uniform base + lane*16)
__device__ __forceinline__ void gll16(const void* g, void* l) {
  auto lp = reinterpret_cast<__attribute__((address_space(3))) uint32_t*>(
      reinterpret_cast<uintptr_t>(l));
  __builtin_amdgcn_global_load_lds(static_cast<const uint32_t*>(g), lp, 16, 0, 0);
}

// ---------------- cast f32 -> bf16 (4 elems/thread) ----------------
__global__ __launch_bounds__(256) void cast_bf16(const float* __restrict__ in,
                                                 bf16_t* __restrict__ out, long n4) {
  long i = (long)blockIdx.x * 256 + threadIdx.x;
  if (i >= n4) return;
  float4 v = ((const float4*)in)[i];
  bf16x4 o;
  o[0] = (bf16_t)v.x; o[1] = (bf16_t)v.y; o[2] = (bf16_t)v.z; o[3] = (bf16_t)v.w;
  ((bf16x4*)out)[i] = o;
}

// ---------------- transpose+cast w_w (CIN,HID) f32 -> (HID,CIN) bf16 ----------------
__global__ __launch_bounds__(256) void transpose_cast_ww(const float* __restrict__ in,
                                                         bf16_t* __restrict__ out) {
  __shared__ float tile[64 * 66];
  int c0 = blockIdx.y * 64;
  int h0 = blockIdx.x * 64;
#pragma unroll
  for (int k = 0; k < 16; k++) {
    int e = k * 256 + threadIdx.x;
    int r = e >> 6, c = e & 63;
    tile[r * 66 + c] = in[(size_t)(c0 + r) * kHID + h0 + c];
  }
  __syncthreads();
#pragma unroll
  for (int k = 0; k < 16; k++) {
    int e = k * 256 + threadIdx.x;
    int r = e >> 6, c = e & 63;
    out[(size_t)(h0 + r) * kCIN + c0 + c] = (bf16_t)tile[c * 66 + r];
  }
}

// ---------------- batched bf16 transpose (T x T per batch) ----------------
__global__ __launch_bounds__(256) void transpose_bf16(const bf16_t* __restrict__ in,
                                                      bf16_t* __restrict__ out) {
  __shared__ bf16_t tile[64 * 66];
  size_t base = (size_t)blockIdx.z * kT * kT;
  int r0 = blockIdx.y * 64, c0 = blockIdx.x * 64;
#pragma unroll
  for (int k = 0; k < 16; k++) {
    int e = k * 256 + threadIdx.x;
    int r = e >> 6, c = e & 63;
    tile[r * 66 + c] = in[base + (size_t)(r0 + r) * kT + c0 + c];
  }
  __syncthreads();
#pragma unroll
  for (int k = 0; k < 16; k++) {
    int e = k * 256 + threadIdx.x;
    int r = e >> 6, c = e & 63;
    out[base + (size_t)(c0 + r) * kT + r0 + c] = tile[c * 66 + r];
  }
}

// ---------------- mirror upper triangle of S (f32, per-batch TxT) into lower ----------------
__global__ __launch_bounds__(256) void mirror_f32(float* __restrict__ S) {
  const int p = blockIdx.x, q = blockIdx.y;   // 64-elem blocks
  if (p <= q) return;                          // only strictly-lower dest tiles
  __shared__ float tile[64 * 65];
  const size_t base = (size_t)blockIdx.z * kT * kT;
#pragma unroll
  for (int k = 0; k < 16; k++) {
    int e = k * 256 + threadIdx.x;
    int r = e >> 6, c = e & 63;
    tile[r * 65 + c] = S[base + (size_t)(q * 64 + r) * kT + p * 64 + c];
  }
  __syncthreads();
#pragma unroll
  for (int k = 0; k < 16; k++) {
    int e = k * 256 + threadIdx.x;
    int r = e >> 6, c = e & 63;
    S[base + (size_t)(p * 64 + r) * kT + q * 64 + c] = tile[c * 65 + r];
  }
}

// ---------------- xg slice (t,h) of xtphi (ld 3072) -> xgT[b] (h,t) ld 2048 ----------------
__global__ __launch_bounds__(256) void transpose_xg(const bf16_t* __restrict__ xtphi,
                                                    bf16_t* __restrict__ xgT) {
  __shared__ bf16_t tile[64 * 66];
  const int hb = blockIdx.x, tb = blockIdx.y, b = blockIdx.z;
#pragma unroll
  for (int k = 0; k < 16; k++) {
    int e = k * 256 + threadIdx.x;
    int r = e >> 6, c = e & 63;   // r: t, c: h
    tile[r * 66 + c] =
        xtphi[(size_t)(b * kT + tb * 64 + r) * 3072 + 2048 + hb * 64 + c];
  }
  __syncthreads();
#pragma unroll
  for (int k = 0; k < 16; k++) {
    int e = k * 256 + threadIdx.x;
    int r = e >> 6, c = e & 63;   // r: h, c: t
    xgT[(size_t)b * kHID * kT + (size_t)(hb * 64 + r) * kT + tb * 64 + c] =
        tile[c * 66 + r];
  }
}

// ---------------- concat theta_b|phi_b|g_b -> bqkv[3072] ----------------
__global__ __launch_bounds__(256) void concat3(const float* __restrict__ a,
                                               const float* __restrict__ b,
                                               const float* __restrict__ c,
                                               float* __restrict__ o) {
  int i = blockIdx.x * 256 + threadIdx.x;
  if (i >= 3072) return;
  o[i] = i < 1024 ? a[i] : (i < 2048 ? b[i - 1024] : c[i - 2048]);
}

// ---------------- block reductions (4 waves of 64) ----------------
__device__ __forceinline__ float blk_red_max(float v, volatile float* s) {
#pragma unroll
  for (int o = 32; o > 0; o >>= 1) v = fmaxf(v, __shfl_xor(v, o, 64));
  __syncthreads();
  if ((threadIdx.x & 63) == 0) s[threadIdx.x >> 6] = v;
  __syncthreads();
  return fmaxf(fmaxf(s[0], s[1]), fmaxf(s[2], s[3]));
}
__device__ __forceinline__ float blk_red_sum(float v, volatile float* s) {
#pragma unroll
  for (int o = 32; o > 0; o >>= 1) v += __shfl_xor(v, o, 64);
  __syncthreads();
  if ((threadIdx.x & 63) == 0) s[threadIdx.x >> 6] = v;
  __syncthreads();
  return (s[0] + s[1]) + (s[2] + s[3]);
}

// ---------------- bias_e[e] = sum_c emb_w[e,c]*w_b[c] + emb_b[e] ----------------
__global__ __launch_bounds__(256) void bias_e_kernel(const float* __restrict__ emb_w,
                                                     const float* __restrict__ w_b,
                                                     const float* __restrict__ emb_b,
                                                     float* __restrict__ out) {
  __shared__ float s[4];
  int e = blockIdx.x;
  float acc = 0.f;
  for (int c = threadIdx.x; c < kCIN; c += 256)
    acc += emb_w[(size_t)e * kCIN + c] * w_b[c];
  acc = blk_red_sum(acc, s);
  if (threadIdx.x == 0) out[e] = acc + emb_b[e];
}

// ---------------- fused moca softmax ----------------
__global__ __launch_bounds__(256) void moca_kernel(const float* __restrict__ src,
                                                   bf16_t* __restrict__ dst,
                                                   const float* __restrict__ rou_w,
                                                   const float* __restrict__ rou_b) {
  __shared__ float s[4];
  const int t = blockIdx.x, b = blockIdx.y;
  const size_t T2 = (size_t)kT * kT;
  const float* rA = src + (size_t)(2 * b) * T2 + (size_t)t * kT;
  const float* rB = rA + T2;
  const int base = threadIdx.x * 8;

  float va[8], vb[8];
  {
    float4 a0 = *(const float4*)(rA + base), a1 = *(const float4*)(rA + base + 4);
    float4 b0 = *(const float4*)(rB + base), b1 = *(const float4*)(rB + base + 4);
    va[0]=a0.x; va[1]=a0.y; va[2]=a0.z; va[3]=a0.w; va[4]=a1.x; va[5]=a1.y; va[6]=a1.z; va[7]=a1.w;
    vb[0]=b0.x; vb[1]=b0.y; vb[2]=b0.z; vb[3]=b0.w; vb[4]=b1.x; vb[5]=b1.y; vb[6]=b1.z; vb[7]=b1.w;
  }
  float m = -1e30f;
#pragma unroll
  for (int j = 0; j < 8; j++) m = fmaxf(m, va[j]);
  m = blk_red_max(m, s);
  float acc = 0.f;
#pragma unroll
  for (int j = 0; j < 8; j++) { va[j] = __expf(va[j] - m); acc += va[j]; }
  float invA = 1.f / blk_red_sum(acc, s);

  m = -1e30f;
#pragma unroll
  for (int j = 0; j < 8; j++) m = fmaxf(m, vb[j]);
  m = blk_red_max(m, s);
  acc = 0.f;
#pragma unroll
  for (int j = 0; j < 8; j++) { vb[j] = __expf(vb[j] - m); acc += vb[j]; }
  float invB = 1.f / blk_red_sum(acc, s);

  const float r0 = rou_w[0], r1 = rou_w[1], rb = rou_b[0];
#pragma unroll
  for (int j = 0; j < 8; j++) va[j] = r0 * va[j] * invA + r1 * vb[j] * invB + rb;

  m = -1e30f;
#pragma unroll
  for (int j = 0; j < 8; j++) m = fmaxf(m, va[j]);
  m = blk_red_max(m, s);
  acc = 0.f;
#pragma unroll
  for (int j = 0; j < 8; j++) { va[j] = __expf(va[j] - m); acc += va[j]; }
  float invC = 1.f / blk_red_sum(acc, s);

  bf16x8 o;
#pragma unroll
  for (int j = 0; j < 8; j++) o[j] = (bf16_t)(va[j] * invC);
  *(bf16x8*)(dst + (size_t)b * T2 + (size_t)t * kT + base) = o;
}

// ---------------- NT GEMM: C[m,n] = sum_k A[m,k]*B[n,k]  (bf16 in, fp32 acc) ----------------
// Tile 128x128 x BK64, 256 threads (2x2 waves of 64x64), mfma_f32_16x16x32_bf16.
// Staging: global_load_lds w=16 into two unpadded [128][32] sub-tiles per operand (32 KB LDS).
// TRIANG: linear-indexed upper-triangular tile grid (bn >= bm), for symmetric C.
template <bool OUT_BF16, bool TRIANG>
__global__ __launch_bounds__(256) void gemm_nt(const bf16_t* __restrict__ A,
                                               const bf16_t* __restrict__ B,
                                               void* __restrict__ Cv,
                                               int M, int N, int K, int lda, int ldb,
                                               long strideA, long strideB, long strideC,
                                               const float* __restrict__ biasN,
                                               const float* __restrict__ biasM,
                                               const float* __restrict__ add32) {
  __shared__ bf16_t sA[2 * 128 * 32];  // halves: k-cols [0,32) and [32,64)
  __shared__ bf16_t sB[2 * 128 * 32];

  const int tid = threadIdx.x;
  const int lane = tid & 63, wave = tid >> 6;
  const int wm = wave & 1, wn = wave >> 1;
  const int lm = lane & 15, q = lane >> 4;

  int bm, bn;
  if (TRIANG) {
    const int nb = N / 128;
    int rem = blockIdx.x, t = 0;
    while (rem >= nb - t) { rem -= nb - t; t++; }
    bm = t; bn = t + rem;
  } else {
    bm = blockIdx.x; bn = blockIdx.y;
  }

  A += (size_t)blockIdx.z * strideA;
  B += (size_t)blockIdx.z * strideB;
  const int m0 = bm * 128, n0 = bn * 128;

  f32x4 acc[4][4];
#pragma unroll
  for (int i = 0; i < 4; i++)
#pragma unroll
    for (int j = 0; j < 4; j++)
#pragma unroll
      for (int r = 0; r < 4; r++) acc[i][j][r] = 0.f;

  // staging: wave w deposits rows [w*16, w*16+16) of each 64-row half-tile.
  const int srow = wave * 16 + (lane >> 2);
  const int scol = (lane & 3) * 8;
  const bf16_t* gA0 = A + (size_t)(m0 + srow) * lda + scol;
  const bf16_t* gA1 = gA0 + (size_t)64 * lda;
  const bf16_t* gB0 = B + (size_t)(n0 + srow) * ldb + scol;
  const bf16_t* gB1 = gB0 + (size_t)64 * ldb;
  bf16_t* lA0 = &sA[wave * 512];
  bf16_t* lA1 = &sA[64 * 32 + wave * 512];
  bf16_t* lB0 = &sB[wave * 512];
  bf16_t* lB1 = &sB[64 * 32 + wave * 512];

  for (int k0 = 0; k0 < K; k0 += 64) {
    __syncthreads();
    gll16(gA0 + k0,      lA0);
    gll16(gA0 + k0 + 32, lA0 + 4096);
    gll16(gA1 + k0,      lA1);
    gll16(gA1 + k0 + 32, lA1 + 4096);
    gll16(gB0 + k0,      lB0);
    gll16(gB0 + k0 + 32, lB0 + 4096);
    gll16(gB1 + k0,      lB1);
    gll16(gB1 + k0 + 32, lB1 + 4096);
    __syncthreads();  // vmcnt(0) drain -> staging complete

#pragma unroll
    for (int kk = 0; kk < 2; kk++) {
      bf16x8 af[4], bfr[4];
#pragma unroll
      for (int i = 0; i < 4; i++)
        af[i] = *(const bf16x8*)(&sA[kk * 4096 + (wm * 64 + i * 16 + lm) * 32 + q * 8]);
#pragma unroll
      for (int j = 0; j < 4; j++)
        bfr[j] = *(const bf16x8*)(&sB[kk * 4096 + (wn * 64 + j * 16 + lm) * 32 + q * 8]);
#pragma unroll
      for (int i = 0; i < 4; i++)
#pragma unroll
        for (int j = 0; j < 4; j++)
          acc[i][j] = __builtin_amdgcn_mfma_f32_16x16x32_bf16(af[i], bfr[j], acc[i][j], 0, 0, 0);
    }
  }

  // epilogue: C/D layout col=lane&15, row=(lane>>4)*4+reg
  const size_t cb = (size_t)blockIdx.z * strideC;
#pragma unroll
  for (int i = 0; i < 4; i++) {
    const int gmb = m0 + wm * 64 + i * 16 + q * 4;
#pragma unroll
    for (int j = 0; j < 4; j++) {
      const int gn = n0 + wn * 64 + j * 16 + lm;
      float bn_ = biasN ? biasN[gn] : 0.f;
#pragma unroll
      for (int r = 0; r < 4; r++) {
        const int gm = gmb + r;
        float v = acc[i][j][r] + bn_;
        if (biasM) v += biasM[gm];
        const size_t idx = cb + (size_t)gm * N + gn;
        if (add32) v += add32[idx];
        if (OUT_BF16) ((bf16_t*)Cv)[idx] = (bf16_t)v;
        else          ((float*)Cv)[idx] = v;
      }
    }
  }
}

extern "C" void kernel_launch(void* const* d_in, const int* in_sizes, int n_in,
                              void* d_out, int out_size, void* d_ws, size_t ws_size,
                              hipStream_t stream) {
  const float* x       = (const float*)d_in[0];
  const float* theta_w = (const float*)d_in[1];
  const float* theta_b = (const float*)d_in[2];
  const float* phi_w   = (const float*)d_in[3];
  const float* phi_b   = (const float*)d_in[4];
  const float* g_w     = (const float*)d_in[5];
  const float* g_b     = (const float*)d_in[6];
  const float* rou_w   = (const float*)d_in[7];
  const float* rou_b   = (const float*)d_in[8];
  const float* w_w     = (const float*)d_in[9];
  const float* w_b     = (const float*)d_in[10];
  const float* emb_w   = (const float*)d_in[11];
  const float* emb_b   = (const float*)d_in[12];
  float* out = (float*)d_out;

  char* ws = (char*)d_ws;
  size_t off = 0;
  auto alloc = [&](size_t bytes) -> char* {
    off = (off + 255) & ~(size_t)255;
    char* p = ws + off;
    off += bytes;
    return p;
  };

  const size_t BT = (size_t)kB * kT;         // 8192
  const size_t T2 = (size_t)kT * kT;         // 4M

  // ~219.7 MB total (ws must be >= this; 257.5 MB overflowed in round 1)
  bf16_t* xbf   = (bf16_t*)alloc(BT * kCIN * 2);               // 33.5 MB
  bf16_t* wqkv  = (bf16_t*)alloc((size_t)3 * kHID * kCIN * 2); // 12.6 MB [theta;phi;g]
  bf16_t* embbf = (bf16_t*)alloc((size_t)kEMB * kCIN * 2);     // 1.0 MB
  bf16_t* wwT   = (bf16_t*)alloc((size_t)kHID * kCIN * 2);     // 4.2 MB
  bf16_t* xtphi = (bf16_t*)alloc(BT * 3072 * 2);               // 50.3 MB [xt|xphi|xg]
  bf16_t* xgT   = (bf16_t*)alloc((size_t)kB * kHID * kT * 2);  // 16.8 MB
  bf16_t* mocab = (bf16_t*)alloc((size_t)kB * T2 * 2);         // 33.5 MB
  bf16_t* Mbf   = (bf16_t*)alloc((size_t)kEMB * kHID * 2);     // 0.5 MB
  float*  biase = (float*)alloc((size_t)kEMB * 4);
  float*  bqkv  = (float*)alloc((size_t)3072 * 4);
  float*  S     = (float*)alloc((size_t)kB * T2 * 4);          // 67.1 MB
  // aliases over dead regions:
  bf16_t* mocaT = (bf16_t*)xtphi;                  // xtphi dead after S2 GEMM + transpose_xg
  bf16_t* yT    = (bf16_t*)S;                      // S dead after moca pass B (16.8 MB)
  float*  xe    = (float*)((char*)S + 33554432);   // disjoint from yT (8.4 MB)

  // casts + weight prep
  long n4;
  n4 = (long)(BT * kCIN / 4);
  cast_bf16<<<dim3((n4 + 255) / 256), 256, 0, stream>>>(x, xbf, n4);
  n4 = (long)((size_t)kHID * kCIN / 4);
  cast_bf16<<<dim3((n4 + 255) / 256), 256, 0, stream>>>(theta_w, wqkv, n4);
  cast_bf16<<<dim3((n4 + 255) / 256), 256, 0, stream>>>(phi_w, wqkv + (size_t)kHID * kCIN, n4);
  cast_bf16<<<dim3((n4 + 255) / 256), 256, 0, stream>>>(g_w, wqkv + (size_t)2 * kHID * kCIN, n4);
  n4 = (long)((size_t)kEMB * kCIN / 4);
  cast_bf16<<<dim3((n4 + 255) / 256), 256, 0, stream>>>(emb_w, embbf, n4);
  transpose_cast_ww<<<dim3(kHID / 64, kCIN / 64), 256, 0, stream>>>(w_w, wwT);
  bias_e_kernel<<<dim3(kEMB), 256, 0, stream>>>(emb_w, w_b, emb_b, biase);
  concat3<<<dim3(12), 256, 0, stream>>>(theta_b, phi_b, g_b, bqkv);

  // xtphi = x @ [theta;phi;g]^T + bqkv  (8192 x 3072, K=2048) -> bf16, 1536 blocks
  gemm_nt<true, false><<<dim3(64, 24, 1), 256, 0, stream>>>(
      xbf, wqkv, xtphi, 8192, 3072, 2048, 2048, 2048, 0, 0, 0, bqkv, nullptr, nullptr);
  // M = emb @ w_w  (256 x 1024, K=2048) -> bf16
  gemm_nt<true, false><<<dim3(2, 8, 1), 256, 0, stream>>>(
      embbf, wwT, Mbf, 256, 1024, 2048, 2048, 2048, 0, 0, 0, nullptr, nullptr, nullptr);

  // S <- S1[b] = x[b] @ x[b]^T  fp32, symmetric: upper tiles only (136 of 256) + mirror
  gemm_nt<false, true><<<dim3(136, 1, kB), 256, 0, stream>>>(
      xbf, xbf, S, 2048, 2048, 2048, 2048, 2048,
      (long)(kT * (size_t)kCIN), (long)(kT * (size_t)kCIN), (long)T2,
      nullptr, nullptr, nullptr);
  mirror_f32<<<dim3(32, 32, kB), 256, 0, stream>>>(S);
  // moca pass A: batches 0,1 from S1 pairs (0,1),(2,3)
  moca_kernel<<<dim3(kT, 2), 256, 0, stream>>>(S, mocab, rou_w, rou_b);

  // S <- S2[b] = xphi[b] @ xt[b]^T  fp32 (K=1024, slices of xtphi, ld 3072)
  gemm_nt<false, false><<<dim3(16, 16, kB), 256, 0, stream>>>(
      xtphi + 1024, xtphi, S, 2048, 2048, 1024, 3072, 3072,
      (long)((size_t)kT * 3072), (long)((size_t)kT * 3072), (long)T2,
      nullptr, nullptr, nullptr);
  // moca pass B: batches 2,3 from S2 pairs (0,1),(2,3)
  moca_kernel<<<dim3(kT, 2), 256, 0, stream>>>(S, mocab + 2 * T2, rou_w, rou_b);

  // xgT[b] (h,t) from xg slice of xtphi — MUST run before mocaT overwrites xtphi
  transpose_xg<<<dim3(16, 32, kB), 256, 0, stream>>>(xtphi, xgT);
  // mocaT (reads mocab, writes over dead xtphi region)
  transpose_bf16<<<dim3(kT / 64, kT / 64, kB), 256, 0, stream>>>(mocab, mocaT);

  // yT[b] = mocaT[b] @ xgT[b]^T  (2048 x 1024, K=2048) -> bf16 (over dead S region)
  gemm_nt<true, false><<<dim3(16, 8, kB), 256, 0, stream>>>(
      mocaT, xgT, yT, 2048, 1024, 2048, 2048, 2048,
      (long)T2, (long)((size_t)kHID * kT), (long)(kT * (size_t)kHID),
      nullptr, nullptr, nullptr);
  // xe = x @ emb^T  (8192 x 256, K=2048) fp32
  gemm_nt<false, false><<<dim3(64, 2, 1), 256, 0, stream>>>(
      xbf, embbf, xe, 8192, 256, 2048, 2048, 2048, 0, 0, 0, nullptr, nullptr, nullptr);
  // out = yT @ M^T + xe + bias_e  (8192 x 256, K=1024) fp32 -> d_out
  gemm_nt<false, false><<<dim3(64, 2, 1), 256, 0, stream>>>(
      yT, Mbf, out, 8192, 256, 1024, 1024, 1024, 0, 0, 0, biase, nullptr, xe);
}

// Round 5
// 554.093 us; speedup vs baseline: 1.3858x; 1.1425x over previous
//
#include <hip/hip_runtime.h>
#include <hip/hip_bf16.h>

// Problem constants (fixed by setup_inputs)
constexpr int kB   = 4;
constexpr int kT   = 2048;
constexpr int kCIN = 2048;
constexpr int kHID = 1024;
constexpr int kEMB = 256;

typedef __bf16 bf16_t;
typedef __bf16 bf16x8 __attribute__((ext_vector_type(8)));
typedef __bf16 bf16x4 __attribute__((ext_vector_type(4)));
typedef float  f32x4  __attribute__((ext_vector_type(4)));

// async global->LDS 16B/lane (LDS dest = wave-uniform base + lane*16)
__device__ __forceinline__ void gll16(const void* g, void* l) {
  auto lp = reinterpret_cast<__attribute__((address_space(3))) uint32_t*>(
      reinterpret_cast<uintptr_t>(l));
  __builtin_amdgcn_global_load_lds(static_cast<const uint32_t*>(g), lp, 16, 0, 0);
}

// ---------------- all f32->bf16 casts in ONE dispatch (block-range dispatch) ----------------
// regions (float4 blocks of 256 thr): x:16384 | theta:2048 | phi:2048 | g:2048 | emb:512
__global__ __launch_bounds__(256) void prep_all(const float* __restrict__ x,
                                                const float* __restrict__ th,
                                                const float* __restrict__ ph,
                                                const float* __restrict__ g,
                                                const float* __restrict__ emb,
                                                bf16_t* __restrict__ xbf,
                                                bf16_t* __restrict__ wqkv,
                                                bf16_t* __restrict__ embbf) {
  const int b = blockIdx.x;
  const float* in; bf16_t* out; long i;
  if (b < 16384)      { in = x;   out = xbf;                  i = (long)b * 256 + threadIdx.x; }
  else if (b < 18432) { in = th;  out = wqkv;                 i = (long)(b - 16384) * 256 + threadIdx.x; }
  else if (b < 20480) { in = ph;  out = wqkv + (size_t)kHID * kCIN;     i = (long)(b - 18432) * 256 + threadIdx.x; }
  else if (b < 22528) { in = g;   out = wqkv + (size_t)2 * kHID * kCIN; i = (long)(b - 20480) * 256 + threadIdx.x; }
  else                { in = emb; out = embbf;                i = (long)(b - 22528) * 256 + threadIdx.x; }
  float4 v = ((const float4*)in)[i];
  bf16x4 o;
  o[0] = (bf16_t)v.x; o[1] = (bf16_t)v.y; o[2] = (bf16_t)v.z; o[3] = (bf16_t)v.w;
  ((bf16x4*)out)[i] = o;
}

// ---------------- transpose+cast w_w (CIN,HID) f32 -> (HID,CIN) bf16 ----------------
__global__ __launch_bounds__(256) void transpose_cast_ww(const float* __restrict__ in,
                                                         bf16_t* __restrict__ out) {
  __shared__ float tile[64 * 66];
  int c0 = blockIdx.y * 64;
  int h0 = blockIdx.x * 64;
#pragma unroll
  for (int k = 0; k < 16; k++) {
    int e = k * 256 + threadIdx.x;
    int r = e >> 6, c = e & 63;
    tile[r * 66 + c] = in[(size_t)(c0 + r) * kHID + h0 + c];
  }
  __syncthreads();
#pragma unroll
  for (int k = 0; k < 16; k++) {
    int e = k * 256 + threadIdx.x;
    int r = e >> 6, c = e & 63;
    out[(size_t)(h0 + r) * kCIN + c0 + c] = (bf16_t)tile[c * 66 + r];
  }
}

// ---------------- batched bf16 transpose (T x T per batch) ----------------
__global__ __launch_bounds__(256) void transpose_bf16(const bf16_t* __restrict__ in,
                                                      bf16_t* __restrict__ out) {
  __shared__ bf16_t tile[64 * 66];
  size_t base = (size_t)blockIdx.z * kT * kT;
  int r0 = blockIdx.y * 64, c0 = blockIdx.x * 64;
#pragma unroll
  for (int k = 0; k < 16; k++) {
    int e = k * 256 + threadIdx.x;
    int r = e >> 6, c = e & 63;
    tile[r * 66 + c] = in[base + (size_t)(r0 + r) * kT + c0 + c];
  }
  __syncthreads();
#pragma unroll
  for (int k = 0; k < 16; k++) {
    int e = k * 256 + threadIdx.x;
    int r = e >> 6, c = e & 63;
    out[base + (size_t)(c0 + r) * kT + r0 + c] = tile[c * 66 + r];
  }
}

// ---------------- mirror upper triangle of S (bf16, per-batch TxT) into lower ----------------
__global__ __launch_bounds__(256) void mirror_bf16(bf16_t* __restrict__ S) {
  const int p = blockIdx.x, q = blockIdx.y;   // 64-elem blocks
  if (p <= q) return;                          // only strictly-lower dest tiles
  __shared__ bf16_t tile[64 * 66];
  const size_t base = (size_t)blockIdx.z * kT * kT;
#pragma unroll
  for (int k = 0; k < 16; k++) {
    int e = k * 256 + threadIdx.x;
    int r = e >> 6, c = e & 63;
    tile[r * 66 + c] = S[base + (size_t)(q * 64 + r) * kT + p * 64 + c];
  }
  __syncthreads();
#pragma unroll
  for (int k = 0; k < 16; k++) {
    int e = k * 256 + threadIdx.x;
    int r = e >> 6, c = e & 63;
    S[base + (size_t)(p * 64 + r) * kT + q * 64 + c] = tile[c * 66 + r];
  }
}

// ---------------- xg slice (t,h) of xtphi (ld 3072) -> xgT[b] (h,t) ld 2048 ----------------
__global__ __launch_bounds__(256) void transpose_xg(const bf16_t* __restrict__ xtphi,
                                                    bf16_t* __restrict__ xgT) {
  __shared__ bf16_t tile[64 * 66];
  const int hb = blockIdx.x, tb = blockIdx.y, b = blockIdx.z;
#pragma unroll
  for (int k = 0; k < 16; k++) {
    int e = k * 256 + threadIdx.x;
    int r = e >> 6, c = e & 63;   // r: t, c: h
    tile[r * 66 + c] =
        xtphi[(size_t)(b * kT + tb * 64 + r) * 3072 + 2048 + hb * 64 + c];
  }
  __syncthreads();
#pragma unroll
  for (int k = 0; k < 16; k++) {
    int e = k * 256 + threadIdx.x;
    int r = e >> 6, c = e & 63;   // r: h, c: t
    xgT[(size_t)b * kHID * kT + (size_t)(hb * 64 + r) * kT + tb * 64 + c] =
        tile[c * 66 + r];
  }
}

// ---------------- block reductions (4 waves of 64) ----------------
__device__ __forceinline__ float blk_red_max(float v, volatile float* s) {
#pragma unroll
  for (int o = 32; o > 0; o >>= 1) v = fmaxf(v, __shfl_xor(v, o, 64));
  __syncthreads();
  if ((threadIdx.x & 63) == 0) s[threadIdx.x >> 6] = v;
  __syncthreads();
  return fmaxf(fmaxf(s[0], s[1]), fmaxf(s[2], s[3]));
}
__device__ __forceinline__ float blk_red_sum(float v, volatile float* s) {
#pragma unroll
  for (int o = 32; o > 0; o >>= 1) v += __shfl_xor(v, o, 64);
  __syncthreads();
  if ((threadIdx.x & 63) == 0) s[threadIdx.x >> 6] = v;
  __syncthreads();
  return (s[0] + s[1]) + (s[2] + s[3]);
}

// ---------------- bias_e (blocks 0..255) + concat3 (blocks 256..267) ----------------
__global__ __launch_bounds__(256) void bias_concat(const float* __restrict__ emb_w,
                                                   const float* __restrict__ w_b,
                                                   const float* __restrict__ emb_b,
                                                   float* __restrict__ biase,
                                                   const float* __restrict__ tb,
                                                   const float* __restrict__ pb,
                                                   const float* __restrict__ gb,
                                                   float* __restrict__ bqkv) {
  if (blockIdx.x < 256) {
    __shared__ float s[4];
    int e = blockIdx.x;
    float acc = 0.f;
    for (int c = threadIdx.x; c < kCIN; c += 256)
      acc += emb_w[(size_t)e * kCIN + c] * w_b[c];
    acc = blk_red_sum(acc, s);
    if (threadIdx.x == 0) biase[e] = acc + emb_b[e];
  } else {
    int i = (blockIdx.x - 256) * 256 + threadIdx.x;
    if (i < 3072)
      bqkv[i] = i < 1024 ? tb[i] : (i < 2048 ? pb[i - 1024] : gb[i - 2048]);
  }
}

// ---------------- fused moca softmax (bf16 scores in) ----------------
__global__ __launch_bounds__(256) void moca_kernel(const bf16_t* __restrict__ src,
                                                   bf16_t* __restrict__ dst,
                                                   const float* __restrict__ rou_w,
                                                   const float* __restrict__ rou_b) {
  __shared__ float s[4];
  const int t = blockIdx.x, b = blockIdx.y;
  const size_t T2 = (size_t)kT * kT;
  const bf16_t* rA = src + (size_t)(2 * b) * T2 + (size_t)t * kT;
  const bf16_t* rB = rA + T2;
  const int base = threadIdx.x * 8;

  float va[8], vb[8];
  {
    bf16x8 a = *(const bf16x8*)(rA + base);
    bf16x8 bb = *(const bf16x8*)(rB + base);
#pragma unroll
    for (int j = 0; j < 8; j++) { va[j] = (float)a[j]; vb[j] = (float)bb[j]; }
  }
  float m = -1e30f;
#pragma unroll
  for (int j = 0; j < 8; j++) m = fmaxf(m, va[j]);
  m = blk_red_max(m, s);
  float acc = 0.f;
#pragma unroll
  for (int j = 0; j < 8; j++) { va[j] = __expf(va[j] - m); acc += va[j]; }
  float invA = 1.f / blk_red_sum(acc, s);

  m = -1e30f;
#pragma unroll
  for (int j = 0; j < 8; j++) m = fmaxf(m, vb[j]);
  m = blk_red_max(m, s);
  acc = 0.f;
#pragma unroll
  for (int j = 0; j < 8; j++) { vb[j] = __expf(vb[j] - m); acc += vb[j]; }
  float invB = 1.f / blk_red_sum(acc, s);

  const float r0 = rou_w[0], r1 = rou_w[1], rb = rou_b[0];
#pragma unroll
  for (int j = 0; j < 8; j++) va[j] = r0 * va[j] * invA + r1 * vb[j] * invB + rb;

  m = -1e30f;
#pragma unroll
  for (int j = 0; j < 8; j++) m = fmaxf(m, va[j]);
  m = blk_red_max(m, s);
  acc = 0.f;
#pragma unroll
  for (int j = 0; j < 8; j++) { va[j] = __expf(va[j] - m); acc += va[j]; }
  float invC = 1.f / blk_red_sum(acc, s);

  bf16x8 o;
#pragma unroll
  for (int j = 0; j < 8; j++) o[j] = (bf16_t)(va[j] * invC);
  *(bf16x8*)(dst + (size_t)b * T2 + (size_t)t * kT + base) = o;
}

// ---------------- NT GEMM: C[m,n] = sum_k A[m,k]*B[n,k] (+ A2,B2 second K-segment) -------
// Tile 128x128 x BK64, 256 threads (2x2 waves of 64x64), mfma_f32_16x16x32_bf16.
// Staging: global_load_lds w=16 into two unpadded [128][32] sub-tiles per operand (32 KB LDS).
// TRIANG: linear-indexed upper-triangular tile grid (bn >= bm), for symmetric C.
template <bool OUT_BF16, bool TRIANG>
__global__ __launch_bounds__(256) void gemm_nt(const bf16_t* __restrict__ A,
                                               const bf16_t* __restrict__ B,
                                               const bf16_t* __restrict__ A2,
                                               const bf16_t* __restrict__ B2,
                                               void* __restrict__ Cv,
                                               int M, int N, int K, int K2,
                                               int lda, int ldb, int lda2, int ldb2,
                                               long strideA, long strideB, long strideC,
                                               const float* __restrict__ biasN,
                                               const float* __restrict__ biasM) {
  __shared__ bf16_t sA[2 * 128 * 32];  // halves: k-cols [0,32) and [32,64)
  __shared__ bf16_t sB[2 * 128 * 32];

  const int tid = threadIdx.x;
  const int lane = tid & 63, wave = tid >> 6;
  const int wm = wave & 1, wn = wave >> 1;
  const int lm = lane & 15, q = lane >> 4;

  int bm, bn;
  if (TRIANG) {
    const int nb = N / 128;
    int rem = blockIdx.x, t = 0;
    while (rem >= nb - t) { rem -= nb - t; t++; }
    bm = t; bn = t + rem;
  } else {
    bm = blockIdx.x; bn = blockIdx.y;
  }

  const int m0 = bm * 128, n0 = bn * 128;

  f32x4 acc[4][4];
#pragma unroll
  for (int i = 0; i < 4; i++)
#pragma unroll
    for (int j = 0; j < 4; j++)
#pragma unroll
      for (int r = 0; r < 4; r++) acc[i][j][r] = 0.f;

  const int srow = wave * 16 + (lane >> 2);
  const int scol = (lane & 3) * 8;
  bf16_t* lA0 = &sA[wave * 512];
  bf16_t* lA1 = &sA[64 * 32 + wave * 512];
  bf16_t* lB0 = &sB[wave * 512];
  bf16_t* lB1 = &sB[64 * 32 + wave * 512];

  const bf16_t* As[2] = {A, A2};
  const bf16_t* Bs[2] = {B, B2};
  const int Ks[2] = {K, K2}, ldas[2] = {lda, lda2}, ldbs[2] = {ldb, ldb2};

  for (int seg = 0; seg < 2; seg++) {
    const int Kseg = Ks[seg];
    if (Kseg == 0) continue;
    const bf16_t* Ab = As[seg] + (size_t)blockIdx.z * strideA;
    const bf16_t* Bb = Bs[seg] + (size_t)blockIdx.z * strideB;
    const int la = ldas[seg], lb = ldbs[seg];
    const bf16_t* gA0 = Ab + (size_t)(m0 + srow) * la + scol;
    const bf16_t* gA1 = gA0 + (size_t)64 * la;
    const bf16_t* gB0 = Bb + (size_t)(n0 + srow) * lb + scol;
    const bf16_t* gB1 = gB0 + (size_t)64 * lb;

    for (int k0 = 0; k0 < Kseg; k0 += 64) {
      __syncthreads();
      gll16(gA0 + k0,      lA0);
      gll16(gA0 + k0 + 32, lA0 + 4096);
      gll16(gA1 + k0,      lA1);
      gll16(gA1 + k0 + 32, lA1 + 4096);
      gll16(gB0 + k0,      lB0);
      gll16(gB0 + k0 + 32, lB0 + 4096);
      gll16(gB1 + k0,      lB1);
      gll16(gB1 + k0 + 32, lB1 + 4096);
      __syncthreads();  // vmcnt(0) drain -> staging complete

#pragma unroll
      for (int kk = 0; kk < 2; kk++) {
        bf16x8 af[4], bfr[4];
#pragma unroll
        for (int i = 0; i < 4; i++)
          af[i] = *(const bf16x8*)(&sA[kk * 4096 + (wm * 64 + i * 16 + lm) * 32 + q * 8]);
#pragma unroll
        for (int j = 0; j < 4; j++)
          bfr[j] = *(const bf16x8*)(&sB[kk * 4096 + (wn * 64 + j * 16 + lm) * 32 + q * 8]);
#pragma unroll
        for (int i = 0; i < 4; i++)
#pragma unroll
          for (int j = 0; j < 4; j++)
            acc[i][j] = __builtin_amdgcn_mfma_f32_16x16x32_bf16(af[i], bfr[j], acc[i][j], 0, 0, 0);
      }
    }
  }

  // epilogue: C/D layout col=lane&15, row=(lane>>4)*4+reg
  const size_t cb = (size_t)blockIdx.z * strideC;
#pragma unroll
  for (int i = 0; i < 4; i++) {
    const int gmb = m0 + wm * 64 + i * 16 + q * 4;
#pragma unroll
    for (int j = 0; j < 4; j++) {
      const int gn = n0 + wn * 64 + j * 16 + lm;
      float bn_ = biasN ? biasN[gn] : 0.f;
#pragma unroll
      for (int r = 0; r < 4; r++) {
        const int gm = gmb + r;
        float v = acc[i][j][r] + bn_;
        if (biasM) v += biasM[gm];
        const size_t idx = cb + (size_t)gm * N + gn;
        if (OUT_BF16) ((bf16_t*)Cv)[idx] = (bf16_t)v;
        else          ((float*)Cv)[idx] = v;
      }
    }
  }
}

extern "C" void kernel_launch(void* const* d_in, const int* in_sizes, int n_in,
                              void* d_out, int out_size, void* d_ws, size_t ws_size,
                              hipStream_t stream) {
  const float* x       = (const float*)d_in[0];
  const float* theta_w = (const float*)d_in[1];
  const float* theta_b = (const float*)d_in[2];
  const float* phi_w   = (const float*)d_in[3];
  const float* phi_b   = (const float*)d_in[4];
  const float* g_w     = (const float*)d_in[5];
  const float* g_b     = (const float*)d_in[6];
  const float* rou_w   = (const float*)d_in[7];
  const float* rou_b   = (const float*)d_in[8];
  const float* w_w     = (const float*)d_in[9];
  const float* w_b     = (const float*)d_in[10];
  const float* emb_w   = (const float*)d_in[11];
  const float* emb_b   = (const float*)d_in[12];
  float* out = (float*)d_out;

  char* ws = (char*)d_ws;
  size_t off = 0;
  auto alloc = [&](size_t bytes) -> char* {
    off = (off + 255) & ~(size_t)255;
    char* p = ws + off;
    off += bytes;
    return p;
  };

  const size_t BT = (size_t)kB * kT;         // 8192
  const size_t T2 = (size_t)kT * kT;         // 4M

  // ~186 MB total
  bf16_t* xbf   = (bf16_t*)alloc(BT * kCIN * 2);               // 33.5 MB
  bf16_t* wqkv  = (bf16_t*)alloc((size_t)3 * kHID * kCIN * 2); // 12.6 MB [theta;phi;g]
  bf16_t* embbf = (bf16_t*)alloc((size_t)kEMB * kCIN * 2);     // 1.0 MB
  bf16_t* wwT   = (bf16_t*)alloc((size_t)kHID * kCIN * 2);     // 4.2 MB
  bf16_t* xtphi = (bf16_t*)alloc(BT * 3072 * 2);               // 50.3 MB [xt|xphi|xg]
  bf16_t* xgT   = (bf16_t*)alloc((size_t)kB * kHID * kT * 2);  // 16.8 MB
  bf16_t* mocab = (bf16_t*)alloc((size_t)kB * T2 * 2);         // 33.5 MB
  bf16_t* Mbf   = (bf16_t*)alloc((size_t)kEMB * kHID * 2);     // 0.5 MB
  float*  biase = (float*)alloc((size_t)kEMB * 4);
  float*  bqkv  = (float*)alloc((size_t)3072 * 4);
  bf16_t* S     = (bf16_t*)alloc((size_t)kB * T2 * 2);         // 33.5 MB (bf16 scores)
  // aliases over dead regions:
  bf16_t* mocaT = (bf16_t*)xtphi;   // xtphi dead after S2 GEMM + transpose_xg (needs 33.5)
  bf16_t* yT    = (bf16_t*)S;       // S dead after moca pass B (needs 16.8 <= 33.5)

  // prep: all casts in one dispatch; bias_e + bias concat in one
  prep_all<<<dim3(23040), 256, 0, stream>>>(x, theta_w, phi_w, g_w, emb_w,
                                            xbf, wqkv, embbf);
  transpose_cast_ww<<<dim3(kHID / 64, kCIN / 64), 256, 0, stream>>>(w_w, wwT);
  bias_concat<<<dim3(268), 256, 0, stream>>>(emb_w, w_b, emb_b, biase,
                                             theta_b, phi_b, g_b, bqkv);

  // xtphi = x @ [theta;phi;g]^T + bqkv  (8192 x 3072, K=2048) -> bf16
  gemm_nt<true, false><<<dim3(64, 24, 1), 256, 0, stream>>>(
      xbf, wqkv, nullptr, nullptr, xtphi, 8192, 3072, 2048, 0,
      2048, 2048, 0, 0, 0, 0, 0, bqkv, nullptr);
  // M = emb @ w_w  (256 x 1024, K=2048) -> bf16
  gemm_nt<true, false><<<dim3(2, 8, 1), 256, 0, stream>>>(
      embbf, wwT, nullptr, nullptr, Mbf, 256, 1024, 2048, 0,
      2048, 2048, 0, 0, 0, 0, 0, nullptr, nullptr);

  // S <- S1[b] = x[b] @ x[b]^T  bf16, symmetric: upper tiles only (136 of 256) + mirror
  gemm_nt<true, true><<<dim3(136, 1, kB), 256, 0, stream>>>(
      xbf, xbf, nullptr, nullptr, S, 2048, 2048, 2048, 0,
      2048, 2048, 0, 0,
      (long)(kT * (size_t)kCIN), (long)(kT * (size_t)kCIN), (long)T2,
      nullptr, nullptr);
  mirror_bf16<<<dim3(32, 32, kB), 256, 0, stream>>>(S);
  // moca pass A: batches 0,1 from S1 pairs (0,1),(2,3)
  moca_kernel<<<dim3(kT, 2), 256, 0, stream>>>(S, mocab, rou_w, rou_b);

  // S <- S2[b] = xphi[b] @ xt[b]^T  bf16 (K=1024, slices of xtphi, ld 3072)
  gemm_nt<true, false><<<dim3(16, 16, kB), 256, 0, stream>>>(
      xtphi + 1024, xtphi, nullptr, nullptr, S, 2048, 2048, 1024, 0,
      3072, 3072, 0, 0,
      (long)((size_t)kT * 3072), (long)((size_t)kT * 3072), (long)T2,
      nullptr, nullptr);
  // moca pass B: batches 2,3 from S2 pairs (0,1),(2,3)
  moca_kernel<<<dim3(kT, 2), 256, 0, stream>>>(S, mocab + 2 * T2, rou_w, rou_b);

  // xgT[b] (h,t) from xg slice of xtphi — MUST run before mocaT overwrites xtphi
  transpose_xg<<<dim3(16, 32, kB), 256, 0, stream>>>(xtphi, xgT);
  // mocaT (reads mocab, writes over dead xtphi region)
  transpose_bf16<<<dim3(kT / 64, kT / 64, kB), 256, 0, stream>>>(mocab, mocaT);

  // yT[b] = mocaT[b] @ xgT[b]^T  (2048 x 1024, K=2048) -> bf16 (over dead S region)
  gemm_nt<true, false><<<dim3(16, 8, kB), 256, 0, stream>>>(
      mocaT, xgT, nullptr, nullptr, yT, 2048, 1024, 2048, 0,
      2048, 2048, 0, 0,
      (long)T2, (long)((size_t)kHID * kT), (long)(kT * (size_t)kHID),
      nullptr, nullptr);

  // out = yT @ M^T (K=1024) + x @ emb^T (K=2048) + bias_e  -> fp32 d_out (dual-K fused)
  gemm_nt<false, false><<<dim3(64, 2, 1), 256, 0, stream>>>(
      yT, Mbf, xbf, embbf, out, 8192, 256, 1024, 2048,
      1024, 1024, 2048, 2048, 0, 0, 0, biase, nullptr);
}

// Round 6
// 523.186 us; speedup vs baseline: 1.4676x; 1.0591x over previous
//
#include <hip/hip_runtime.h>
#include <hip/hip_bf16.h>

constexpr int kB   = 4;
constexpr int kT   = 2048;
constexpr int kCIN = 2048;
constexpr int kHID = 1024;
constexpr int kEMB = 256;

typedef __bf16 bf16_t;
typedef __bf16 bf16x8 __attribute__((ext_vector_type(8)));
typedef __bf16 bf16x4 __attribute__((ext_vector_type(4)));
typedef float  f32x4  __attribute__((ext_vector_type(4)));

// async global->LDS 16B/lane (LDS dest = wave-uniform base + lane*16)
__device__ __forceinline__ void gll16(const void* g, void* l) {
  auto lp = reinterpret_cast<__attribute__((address_space(3))) uint32_t*>(
      reinterpret_cast<uintptr_t>(l));
  __builtin_amdgcn_global_load_lds(static_cast<const uint32_t*>(g), lp, 16, 0, 0);
}

// ================= GEMM core: C[m,n] += / = sum_k A[m,k]*B[n,k] ===================
// 128x128 tile, BK=64, 256 thr (2x2 waves of 64x64), mfma_f32_16x16x32_bf16.
// MODE 0: bf16 store, 2: f32 atomicAdd. A,B pre-offset (batch, k-slice). Klen % 64 == 0.
template <int MODE>
__device__ __forceinline__ void gemm_core(bf16_t* sA, bf16_t* sB,
                                          const bf16_t* A, const bf16_t* B, void* Cv,
                                          int lda, int ldb, int ldc,
                                          int m0, int n0, int Klen,
                                          const float* biasN) {
  const int tid = threadIdx.x;
  const int lane = tid & 63, wave = tid >> 6;
  const int wm = wave & 1, wn = wave >> 1;
  const int lm = lane & 15, q = lane >> 4;

  f32x4 acc[4][4];
#pragma unroll
  for (int i = 0; i < 4; i++)
#pragma unroll
    for (int j = 0; j < 4; j++)
#pragma unroll
      for (int r = 0; r < 4; r++) acc[i][j][r] = 0.f;

  const int srow = wave * 16 + (lane >> 2);
  const int scol = (lane & 3) * 8;
  const bf16_t* gA0 = A + (size_t)(m0 + srow) * lda + scol;
  const bf16_t* gA1 = gA0 + (size_t)64 * lda;
  const bf16_t* gB0 = B + (size_t)(n0 + srow) * ldb + scol;
  const bf16_t* gB1 = gB0 + (size_t)64 * ldb;
  bf16_t* lA0 = &sA[wave * 512];
  bf16_t* lA1 = &sA[64 * 32 + wave * 512];
  bf16_t* lB0 = &sB[wave * 512];
  bf16_t* lB1 = &sB[64 * 32 + wave * 512];

  for (int k0 = 0; k0 < Klen; k0 += 64) {
    __syncthreads();
    gll16(gA0 + k0,      lA0);
    gll16(gA0 + k0 + 32, lA0 + 4096);
    gll16(gA1 + k0,      lA1);
    gll16(gA1 + k0 + 32, lA1 + 4096);
    gll16(gB0 + k0,      lB0);
    gll16(gB0 + k0 + 32, lB0 + 4096);
    gll16(gB1 + k0,      lB1);
    gll16(gB1 + k0 + 32, lB1 + 4096);
    __syncthreads();

#pragma unroll
    for (int kk = 0; kk < 2; kk++) {
      bf16x8 af[4], bfr[4];
#pragma unroll
      for (int i = 0; i < 4; i++)
        af[i] = *(const bf16x8*)(&sA[kk * 4096 + (wm * 64 + i * 16 + lm) * 32 + q * 8]);
#pragma unroll
      for (int j = 0; j < 4; j++)
        bfr[j] = *(const bf16x8*)(&sB[kk * 4096 + (wn * 64 + j * 16 + lm) * 32 + q * 8]);
#pragma unroll
      for (int i = 0; i < 4; i++)
#pragma unroll
        for (int j = 0; j < 4; j++)
          acc[i][j] = __builtin_amdgcn_mfma_f32_16x16x32_bf16(af[i], bfr[j], acc[i][j], 0, 0, 0);
    }
  }

  // epilogue: C/D layout col=lane&15, row=(lane>>4)*4+reg
#pragma unroll
  for (int i = 0; i < 4; i++) {
    const int gmb = m0 + wm * 64 + i * 16 + q * 4;
#pragma unroll
    for (int j = 0; j < 4; j++) {
      const int gn = n0 + wn * 64 + j * 16 + lm;
      float bn_ = biasN ? biasN[gn] : 0.f;
#pragma unroll
      for (int r = 0; r < 4; r++) {
        const int gm = gmb + r;
        float v = acc[i][j][r] + bn_;
        const size_t idx = (size_t)gm * ldc + gn;
        if (MODE == 0) ((bf16_t*)Cv)[idx] = (bf16_t)v;
        else           atomicAdd(&((float*)Cv)[idx], v);
      }
    }
  }
}

// ================= dispatch 1: all prep (casts + w_w transpose + biases) ===========
// blocks: x-cast 16384 | th 2048 | ph 2048 | g 2048 | emb 512 | wwT 512 | bias 268
__global__ __launch_bounds__(256) void k_prep(const float* __restrict__ x,
                                              const float* __restrict__ th,
                                              const float* __restrict__ ph,
                                              const float* __restrict__ g,
                                              const float* __restrict__ emb,
                                              const float* __restrict__ w_w,
                                              const float* __restrict__ w_b,
                                              const float* __restrict__ emb_b,
                                              const float* __restrict__ tb,
                                              const float* __restrict__ pb,
                                              const float* __restrict__ gb,
                                              bf16_t* __restrict__ xbf,
                                              bf16_t* __restrict__ wqkv,
                                              bf16_t* __restrict__ embbf,
                                              bf16_t* __restrict__ wwT,
                                              float* __restrict__ biase,
                                              float* __restrict__ bqkv) {
  __shared__ float tile[64 * 66];
  const int b = blockIdx.x;
  if (b < 23040) {  // casts
    const float* in; bf16_t* out; long i;
    if (b < 16384)      { in = x;   out = xbf;                          i = (long)b * 256 + threadIdx.x; }
    else if (b < 18432) { in = th;  out = wqkv;                         i = (long)(b - 16384) * 256 + threadIdx.x; }
    else if (b < 20480) { in = ph;  out = wqkv + (size_t)kHID * kCIN;   i = (long)(b - 18432) * 256 + threadIdx.x; }
    else if (b < 22528) { in = g;   out = wqkv + (size_t)2 * kHID * kCIN; i = (long)(b - 20480) * 256 + threadIdx.x; }
    else                { in = emb; out = embbf;                        i = (long)(b - 22528) * 256 + threadIdx.x; }
    float4 v = ((const float4*)in)[i];
    bf16x4 o;
    o[0] = (bf16_t)v.x; o[1] = (bf16_t)v.y; o[2] = (bf16_t)v.z; o[3] = (bf16_t)v.w;
    ((bf16x4*)out)[i] = o;
  } else if (b < 23552) {  // w_w (CIN,HID) -> wwT (HID,CIN), 16 x 32 tiles
    int j = b - 23040;
    int h0 = (j & 15) * 64, c0 = (j >> 4) * 64;
#pragma unroll
    for (int k = 0; k < 16; k++) {
      int e = k * 256 + threadIdx.x;
      int r = e >> 6, c = e & 63;
      tile[r * 66 + c] = w_w[(size_t)(c0 + r) * kHID + h0 + c];
    }
    __syncthreads();
#pragma unroll
    for (int k = 0; k < 16; k++) {
      int e = k * 256 + threadIdx.x;
      int r = e >> 6, c = e & 63;
      wwT[(size_t)(h0 + r) * kCIN + c0 + c] = (bf16_t)tile[c * 66 + r];
    }
  } else if (b < 23808) {  // bias_e
    int e = b - 23552;
    float acc = 0.f;
    for (int c = threadIdx.x; c < kCIN; c += 256)
      acc += emb[(size_t)e * kCIN + c] * w_b[c];
#pragma unroll
    for (int o = 32; o > 0; o >>= 1) acc += __shfl_xor(acc, o, 64);
    __syncthreads();
    if ((threadIdx.x & 63) == 0) tile[threadIdx.x >> 6] = acc;
    __syncthreads();
    if (threadIdx.x == 0) biase[e] = tile[0] + tile[1] + tile[2] + tile[3] + emb_b[e];
  } else {  // concat biases -> bqkv[3072]
    int i = (b - 23808) * 256 + threadIdx.x;
    if (i < 3072)
      bqkv[i] = i < 1024 ? tb[i] : (i < 2048 ? pb[i - 1024] : gb[i - 2048]);
  }
}

// ================= dispatch 2: QKV(1536) + S1-tri(544) + M(16) = 2096 blocks =======
__global__ __launch_bounds__(256) void k_mega1(const bf16_t* __restrict__ xbf,
                                               const bf16_t* __restrict__ wqkv,
                                               const bf16_t* __restrict__ embbf,
                                               const bf16_t* __restrict__ wwT,
                                               bf16_t* __restrict__ xtphi,
                                               bf16_t* __restrict__ S1,
                                               bf16_t* __restrict__ Mbf,
                                               const float* __restrict__ bqkv) {
  __shared__ bf16_t sA[8192], sB[8192];
  const int bid = blockIdx.x;
  if (bid < 1536) {  // xtphi = x @ wqkv^T + bqkv  (8192 x 3072, K=2048)
    int bm = bid & 63, bn = bid >> 6;
    gemm_core<0>(sA, sB, xbf, wqkv, xtphi, 2048, 2048, 3072,
                 bm * 128, bn * 128, 2048, bqkv);
  } else if (bid < 2080) {  // S1[z] = x[z] @ x[z]^T, upper triangular tiles (nb=16)
    int s = bid - 1536;
    int z = s / 136, t = s % 136;
    int r = 0;
    while (t >= 16 - r) { t -= 16 - r; r++; }
    const bf16_t* Az = xbf + (size_t)z * kT * kCIN;
    gemm_core<0>(sA, sB, Az, Az, S1 + (size_t)z * kT * kT, 2048, 2048, 2048,
                 r * 128, (r + t) * 128, 2048, nullptr);
  } else {  // M = emb @ w_w  (256 x 1024, K=2048)
    int m = bid - 2080;
    gemm_core<0>(sA, sB, embbf, wwT, Mbf, 2048, 2048, 1024,
                 (m & 1) * 128, (m >> 1) * 128, 2048, nullptr);
  }
}

// ====== dispatch 3: S2(1024) + mirror(1984) + xg-transpose(2048) + zero-out(2048) ==
__global__ __launch_bounds__(256) void k_mid(const bf16_t* __restrict__ xtphi,
                                             bf16_t* __restrict__ S2,
                                             bf16_t* __restrict__ S1,
                                             bf16_t* __restrict__ xgT,
                                             float* __restrict__ out) {
  __shared__ bf16_t sA[8192], sB[8192];
  const int bid = blockIdx.x;
  const size_t T2 = (size_t)kT * kT;
  if (bid < 1024) {  // S2[z] = xphi[z] @ xt[z]^T (K=1024, slices of xtphi ld 3072)
    int bm = bid & 15, bn = (bid >> 4) & 15, z = bid >> 8;
    const bf16_t* base = xtphi + (size_t)z * kT * 3072;
    gemm_core<0>(sA, sB, base + 1024, base, S2 + (size_t)z * T2, 3072, 3072, 2048,
                 bm * 128, bn * 128, 1024, nullptr);
  } else if (bid < 3008) {  // mirror S1 upper -> lower (64x64 tiles, p>q), 496/batch
    int j = bid - 1024;
    int z = j / 496, t = j % 496, qq = 0;
    while (t >= 31 - qq) { t -= 31 - qq; qq++; }
    int p = qq + 1 + t;
    bf16_t* tile = sA;  // 64*66 = 4224 <= 8192
    const size_t base = (size_t)z * T2;
#pragma unroll
    for (int k = 0; k < 16; k++) {
      int e = k * 256 + threadIdx.x;
      int r = e >> 6, c = e & 63;
      tile[r * 66 + c] = S1[base + (size_t)(qq * 64 + r) * kT + p * 64 + c];
    }
    __syncthreads();
#pragma unroll
    for (int k = 0; k < 16; k++) {
      int e = k * 256 + threadIdx.x;
      int r = e >> 6, c = e & 63;
      S1[base + (size_t)(p * 64 + r) * kT + qq * 64 + c] = tile[c * 66 + r];
    }
  } else if (bid < 5056) {  // xgT[z](h,t) from xg slice of xtphi
    int j = bid - 3008;
    int hb = j & 15, tb = (j >> 4) & 31, z = j >> 9;
    bf16_t* tile = sA;
#pragma unroll
    for (int k = 0; k < 16; k++) {
      int e = k * 256 + threadIdx.x;
      int r = e >> 6, c = e & 63;  // r: t, c: h
      tile[r * 66 + c] = xtphi[(size_t)(z * kT + tb * 64 + r) * 3072 + 2048 + hb * 64 + c];
    }
    __syncthreads();
#pragma unroll
    for (int k = 0; k < 16; k++) {
      int e = k * 256 + threadIdx.x;
      int r = e >> 6, c = e & 63;  // r: h, c: t
      xgT[(size_t)z * kHID * kT + (size_t)(hb * 64 + r) * kT + tb * 64 + c] = tile[c * 66 + r];
    }
  } else {  // zero d_out (2M f32 = 524288 float4)
    long i = (long)(bid - 5056) * 256 + threadIdx.x;
    ((float4*)out)[i] = make_float4(0.f, 0.f, 0.f, 0.f);
  }
}

// ================= dispatch 4: moca (both passes) ==================================
// moca[b] = softmax(r0*softmax(src[pb]) + r1*softmax(src[pb+1]) + rb); rows over s.
// b<2 -> src=S1, pb=2b ; b>=2 -> src=S2, pb=2(b-2).
__global__ __launch_bounds__(256) void k_moca(const bf16_t* __restrict__ S1,
                                              const bf16_t* __restrict__ S2,
                                              bf16_t* __restrict__ dst,
                                              const float* __restrict__ rou_w,
                                              const float* __restrict__ rou_b) {
  __shared__ float s[4];
  const int t = blockIdx.x, b = blockIdx.y;
  const size_t T2 = (size_t)kT * kT;
  const bf16_t* src = (b < 2) ? S1 : S2;
  const int pb = (b < 2) ? 2 * b : 2 * (b - 2);
  const bf16_t* rA = src + (size_t)pb * T2 + (size_t)t * kT;
  const bf16_t* rB = rA + T2;
  const int base = threadIdx.x * 8;

  float va[8], vb[8];
  {
    bf16x8 a = *(const bf16x8*)(rA + base);
    bf16x8 bb = *(const bf16x8*)(rB + base);
#pragma unroll
    for (int j = 0; j < 8; j++) { va[j] = (float)a[j]; vb[j] = (float)bb[j]; }
  }
  auto red_max = [&](float v) {
#pragma unroll
    for (int o = 32; o > 0; o >>= 1) v = fmaxf(v, __shfl_xor(v, o, 64));
    __syncthreads();
    if ((threadIdx.x & 63) == 0) s[threadIdx.x >> 6] = v;
    __syncthreads();
    return fmaxf(fmaxf(s[0], s[1]), fmaxf(s[2], s[3]));
  };
  auto red_sum = [&](float v) {
#pragma unroll
    for (int o = 32; o > 0; o >>= 1) v += __shfl_xor(v, o, 64);
    __syncthreads();
    if ((threadIdx.x & 63) == 0) s[threadIdx.x >> 6] = v;
    __syncthreads();
    return (s[0] + s[1]) + (s[2] + s[3]);
  };

  float m = -1e30f, acc;
#pragma unroll
  for (int j = 0; j < 8; j++) m = fmaxf(m, va[j]);
  m = red_max(m); acc = 0.f;
#pragma unroll
  for (int j = 0; j < 8; j++) { va[j] = __expf(va[j] - m); acc += va[j]; }
  float invA = 1.f / red_sum(acc);

  m = -1e30f;
#pragma unroll
  for (int j = 0; j < 8; j++) m = fmaxf(m, vb[j]);
  m = red_max(m); acc = 0.f;
#pragma unroll
  for (int j = 0; j < 8; j++) { vb[j] = __expf(vb[j] - m); acc += vb[j]; }
  float invB = 1.f / red_sum(acc);

  const float r0 = rou_w[0], r1 = rou_w[1], rb = rou_b[0];
#pragma unroll
  for (int j = 0; j < 8; j++) va[j] = r0 * va[j] * invA + r1 * vb[j] * invB + rb;

  m = -1e30f;
#pragma unroll
  for (int j = 0; j < 8; j++) m = fmaxf(m, va[j]);
  m = red_max(m); acc = 0.f;
#pragma unroll
  for (int j = 0; j < 8; j++) { va[j] = __expf(va[j] - m); acc += va[j]; }
  float invC = 1.f / red_sum(acc);

  bf16x8 o;
#pragma unroll
  for (int j = 0; j < 8; j++) o[j] = (bf16_t)(va[j] * invC);
  *(bf16x8*)(dst + (size_t)b * T2 + (size_t)t * kT + base) = o;
}

// ================= dispatch 5: mocab -> mocaT (batched TxT transpose) ==============
__global__ __launch_bounds__(256) void k_mocaT(const bf16_t* __restrict__ in,
                                               bf16_t* __restrict__ out) {
  __shared__ bf16_t tile[64 * 66];
  size_t base = (size_t)blockIdx.z * kT * kT;
  int r0 = blockIdx.y * 64, c0 = blockIdx.x * 64;
#pragma unroll
  for (int k = 0; k < 16; k++) {
    int e = k * 256 + threadIdx.x;
    int r = e >> 6, c = e & 63;
    tile[r * 66 + c] = in[base + (size_t)(r0 + r) * kT + c0 + c];
  }
  __syncthreads();
#pragma unroll
  for (int k = 0; k < 16; k++) {
    int e = k * 256 + threadIdx.x;
    int r = e >> 6, c = e & 63;
    out[base + (size_t)(c0 + r) * kT + r0 + c] = tile[c * 66 + r];
  }
}

// ====== dispatch 6: yT GEMM(512) + x@emb^T split-K4 atomic into out (512) ==========
__global__ __launch_bounds__(256) void k_tail1(const bf16_t* __restrict__ mocaT,
                                               const bf16_t* __restrict__ xgT,
                                               bf16_t* __restrict__ yT,
                                               const bf16_t* __restrict__ xbf,
                                               const bf16_t* __restrict__ embbf,
                                               float* __restrict__ out,
                                               const float* __restrict__ biase) {
  __shared__ bf16_t sA[8192], sB[8192];
  const int bid = blockIdx.x;
  if (bid < 512) {  // yT[z] = mocaT[z] @ xgT[z]^T  (2048 x 1024, K=2048)
    int bm = bid & 15, bn = (bid >> 4) & 7, z = bid >> 7;
    gemm_core<0>(sA, sB, mocaT + (size_t)z * kT * kT, xgT + (size_t)z * kHID * kT,
                 yT + (size_t)z * kT * kHID, 2048, 2048, 1024,
                 bm * 128, bn * 128, 2048, nullptr);
  } else {  // out += x @ emb^T slice (K=512 each), + biase on slice 0
    int r = bid - 512;
    int bm = r & 63, bn = (r >> 6) & 1, ks = r >> 7;
    gemm_core<2>(sA, sB, xbf + ks * 512, embbf + ks * 512, out, 2048, 2048, 256,
                 bm * 128, bn * 128, 512, ks == 0 ? biase : nullptr);
  }
}

// ================= dispatch 7: out += yT @ M^T split-K4 atomic (512) ===============
__global__ __launch_bounds__(256) void k_tail2(const bf16_t* __restrict__ yT,
                                               const bf16_t* __restrict__ Mbf,
                                               float* __restrict__ out) {
  __shared__ bf16_t sA[8192], sB[8192];
  const int bid = blockIdx.x;
  int bm = bid & 63, bn = (bid >> 6) & 1, ks = bid >> 7;
  gemm_core<2>(sA, sB, yT + ks * 256, Mbf + ks * 256, out, 1024, 1024, 256,
               bm * 128, bn * 128, 256, nullptr);
}

extern "C" void kernel_launch(void* const* d_in, const int* in_sizes, int n_in,
                              void* d_out, int out_size, void* d_ws, size_t ws_size,
                              hipStream_t stream) {
  const float* x       = (const float*)d_in[0];
  const float* theta_w = (const float*)d_in[1];
  const float* theta_b = (const float*)d_in[2];
  const float* phi_w   = (const float*)d_in[3];
  const float* phi_b   = (const float*)d_in[4];
  const float* g_w     = (const float*)d_in[5];
  const float* g_b     = (const float*)d_in[6];
  const float* rou_w   = (const float*)d_in[7];
  const float* rou_b   = (const float*)d_in[8];
  const float* w_w     = (const float*)d_in[9];
  const float* w_b     = (const float*)d_in[10];
  const float* emb_w   = (const float*)d_in[11];
  const float* emb_b   = (const float*)d_in[12];
  float* out = (float*)d_out;

  char* ws = (char*)d_ws;
  size_t off = 0;
  auto alloc = [&](size_t bytes) -> char* {
    off = (off + 255) & ~(size_t)255;
    char* p = ws + off;
    off += bytes;
    return p;
  };

  const size_t BT = (size_t)kB * kT;   // 8192
  const size_t T2 = (size_t)kT * kT;   // 4M

  // ~220 MB total (< 256 MB; round-1 lesson)
  bf16_t* xbf   = (bf16_t*)alloc(BT * kCIN * 2);               // 33.5 MB
  bf16_t* wqkv  = (bf16_t*)alloc((size_t)3 * kHID * kCIN * 2); // 12.6 MB
  bf16_t* embbf = (bf16_t*)alloc((size_t)kEMB * kCIN * 2);     // 1.0 MB
  bf16_t* wwT   = (bf16_t*)alloc((size_t)kHID * kCIN * 2);     // 4.2 MB
  bf16_t* xtphi = (bf16_t*)alloc(BT * 3072 * 2);               // 50.3 MB [xt|xphi|xg]
  bf16_t* xgT   = (bf16_t*)alloc((size_t)kB * kHID * kT * 2);  // 16.8 MB
  bf16_t* mocab = (bf16_t*)alloc((size_t)kB * T2 * 2);         // 33.5 MB
  bf16_t* Mbf   = (bf16_t*)alloc((size_t)kEMB * kHID * 2);     // 0.5 MB
  float*  biase = (float*)alloc((size_t)kEMB * 4);
  float*  bqkv  = (float*)alloc((size_t)3072 * 4);
  bf16_t* S1    = (bf16_t*)alloc((size_t)kB * T2 * 2);         // 33.5 MB
  bf16_t* S2    = (bf16_t*)alloc((size_t)kB * T2 * 2);         // 33.5 MB
  // aliases over dead regions:
  bf16_t* mocaT = (bf16_t*)xtphi;  // xtphi dead after k_mid (S2 GEMM + xg transpose)
  bf16_t* yT    = (bf16_t*)S2;     // S2 dead after k_moca (needs 16.8 <= 33.5)

  // 1: prep (casts + wwT + bias_e + bqkv)
  k_prep<<<dim3(23820), 256, 0, stream>>>(x, theta_w, phi_w, g_w, emb_w, w_w, w_b,
                                          emb_b, theta_b, phi_b, g_b,
                                          xbf, wqkv, embbf, wwT, biase, bqkv);
  // 2: QKV + S1-triangular + M
  k_mega1<<<dim3(2096), 256, 0, stream>>>(xbf, wqkv, embbf, wwT, xtphi, S1, Mbf, bqkv);
  // 3: S2 + mirror(S1) + xgT + zero(out)
  k_mid<<<dim3(7104), 256, 0, stream>>>(xtphi, S2, S1, xgT, out);
  // 4: moca (both passes)
  k_moca<<<dim3(kT, kB), 256, 0, stream>>>(S1, S2, mocab, rou_w, rou_b);
  // 5: mocaT (overwrites dead xtphi)
  k_mocaT<<<dim3(32, 32, kB), 256, 0, stream>>>(mocab, mocaT);
  // 6: yT GEMM (over dead S2) + x@emb^T split-K atomic + biase
  k_tail1<<<dim3(1024), 256, 0, stream>>>(mocaT, xgT, yT, xbf, embbf, out, biase);
  // 7: out += yT @ M^T split-K atomic
  k_tail2<<<dim3(512), 256, 0, stream>>>(yT, Mbf, out);
}